// Round 8
// baseline (248.650 us; speedup 1.0000x reference)
//
#include <hip/hip_runtime.h>
#include <hip/hip_bf16.h>

#define ICN 512
#define OCN 512
#define RS    136      // padded pixel-plane row stride (cols)
#define NROW  17792    // GEMM N = 139*128 >= 130*136=17680; also C plane stride
#define GUARD 144      // zero guard rows in front of XPT (max shift 137)
#define XROWS 17936    // GUARD + NROW

typedef __attribute__((ext_vector_type(8))) short short8;
typedef __attribute__((ext_vector_type(4))) float f32x4;

__device__ __forceinline__ void gload_lds16(const void* g, void* l) {
  __builtin_amdgcn_global_load_lds(
      (const __attribute__((address_space(1))) void*)g,
      (__attribute__((address_space(3))) void*)l, 16, 0, 0);
}

// ---- fused demod + weight pack: AP[tp][oc][ic] = coef[oc]*w[oc][ic][widx(tp)] ----
__global__ __launch_bounds__(256) void wprep_k(const float* __restrict__ w,
                                               __hip_bfloat16* __restrict__ AP) {
  constexpr int WIDX[9] = {0, 2, 6, 8, 1, 7, 3, 5, 4};  // tap -> ky*3+kx
  const int oc = blockIdx.x;
  const int tid = threadIdx.x, lane = tid & 63, wv = tid >> 6;

  float v[2][9];
  float s = 0.f;
#pragma unroll
  for (int rep = 0; rep < 2; ++rep) {
    const int ic = tid + rep * 256;
    const float* wp = w + ((size_t)oc * ICN + ic) * 9;
#pragma unroll
    for (int j = 0; j < 9; ++j) { v[rep][j] = wp[j]; s += wp[j] * wp[j]; }
  }
#pragma unroll
  for (int o = 32; o > 0; o >>= 1) s += __shfl_down(s, o, 64);
  __shared__ float red[4];
  if (lane == 0) red[wv] = s;
  __syncthreads();
  const float tot = red[0] + red[1] + red[2] + red[3];
  const float scale2 = 1.0f / 4608.0f;
  const float c = sqrtf(scale2) * rsqrtf(scale2 * tot + 1e-8f);

#pragma unroll
  for (int rep = 0; rep < 2; ++rep) {
    const int ic = tid + rep * 256;
#pragma unroll
    for (int tp = 0; tp < 9; ++tp)
      AP[((size_t)tp * OCN + oc) * ICN + ic] = __float2bfloat16(c * v[rep][WIDX[tp]]);
  }
}

// ---- x -> bf16 transposed padded pixel space, via LDS transpose tile ----
// XPT[row][ic], row = GUARD + py*136 + px; valid pixels px-1,py-1 in [0,128)
__global__ __launch_bounds__(256) void packx2_k(const float* __restrict__ x,
                                                unsigned int* __restrict__ XP32) {
  const int py  = blockIdx.x;        // 0..129
  const int ic0 = blockIdx.y * 64;
  const int tid = threadIdx.x;
  const int yy  = py - 1;
  const bool rowvalid = (unsigned)yy < 128u;

  __shared__ __hip_bfloat16 T[128 * 65];   // T[xx][ic_i], padded stride 65

  if (rowvalid) {
    const float4* xr = (const float4*)(x + (size_t)ic0 * 16384 + (size_t)yy * 128);
#pragma unroll
    for (int rep = 0; rep < 8; ++rep) {
      const int idx = rep * 256 + tid;     // 0..2047
      const int x4 = idx & 31, ici = idx >> 5;
      const float4 v = xr[(size_t)ici * 4096 + x4];   // coalesced 16B/lane
      const int xx = x4 * 4;
      T[(xx + 0) * 65 + ici] = __float2bfloat16(v.x);
      T[(xx + 1) * 65 + ici] = __float2bfloat16(v.y);
      T[(xx + 2) * 65 + ici] = __float2bfloat16(v.z);
      T[(xx + 3) * 65 + ici] = __float2bfloat16(v.w);
    }
  }
  __syncthreads();

  const size_t rowbase = (size_t)(GUARD + py * 136) * 256 + (ic0 >> 1);
  // 136 px-rows * 32 u32 = 4352 words; 17 reps of 256
  for (int rep = 0; rep < 17; ++rep) {
    const int idx = rep * 256 + tid;
    const int px = idx >> 5, j = idx & 31;
    unsigned int uv = 0;
    if (rowvalid && (unsigned)(px - 1) < 128u) {
      union { __hip_bfloat16 h[2]; unsigned int u; } cv;
      cv.h[0] = T[(px - 1) * 65 + 2 * j];
      cv.h[1] = T[(px - 1) * 65 + 2 * j + 1];
      uv = cv.u;
    }
    XP32[rowbase + (size_t)px * 256 + j] = uv;   // coalesced 128B/half-wave
  }
}

// ---- zero the guard rows [0,144) and tail rows [17824,17936) of XPT ----
__global__ __launch_bounds__(256) void zguard_k(unsigned int* __restrict__ XP32) {
  const int r = blockIdx.x;                       // 0..255
  const int row = (r < 144) ? r : (r + 17680);    // 144->17824 .. 255->17935
  XP32[(size_t)row * 256 + threadIdx.x] = 0;
}

// ---- MFMA implicit GEMM: C[ph][oc][n] = sum_t sum_ic AP[tp][oc][ic]*XPT[n-sh][ic]
// BK=64 staged as two side-by-side [128][32] sub-buffers (keeps 64B row stride).
// Grid: x = (oc,ph) so the 16 blocks sharing a B-tile are dispatch-adjacent.
// Epilogue writes 0 to pixel-space pad cells so the blur can read branch-free.
__global__ __launch_bounds__(256) void gemm_k(const __hip_bfloat16* __restrict__ AP,
                                              const __hip_bfloat16* __restrict__ XPT,
                                              __hip_bfloat16* __restrict__ C) {
  constexpr int NTt[4]   = {4, 2, 2, 1};
  constexpr int TPO[4]   = {0, 4, 6, 8};
  constexpr int SHIFT[9] = {0, 1, 136, 137, 0, 136, 0, 1, 0};
  constexpr int AR[4]    = {129, 129, 128, 128};  // valid pixel rows per phase
  constexpr int AC[4]    = {129, 128, 129, 128};  // valid pixel cols per phase

  const int ocph = blockIdx.x;                    // 0..15
  const int ph   = ocph & 3;
  const int oc0  = (ocph >> 2) * 128;
  const int n0   = blockIdx.y * 128;
  const int tid = threadIdx.x, lane = tid & 63, wv = tid >> 6;
  const int wr = wv >> 1, wc = wv & 1;

  __shared__ __align__(16) __hip_bfloat16 lA[2][128 * 32];
  __shared__ __align__(16) __hip_bfloat16 lB[2][128 * 32];

  const int srow = tid >> 2;          // 0..63 (staging row)
  const int scol = (tid & 3) * 8;     // staging col within 32-wide sub-buffer

  f32x4 acc[4][4];
#pragma unroll
  for (int m = 0; m < 4; ++m)
#pragma unroll
    for (int n = 0; n < 4; ++n) acc[m][n] = (f32x4){0.f, 0.f, 0.f, 0.f};

  const int total = NTt[ph] * 8;      // 8 x 64-wide K-chunks per tap
  for (int i = 0; i < total; ++i) {
    const int tp = TPO[ph] + (i >> 3);
    const int kc = (i & 7) * 64 + scol;
    const __hip_bfloat16* Ab =
        AP + (size_t)tp * (ICN * OCN) + (size_t)(oc0 + srow) * ICN + kc;
    const __hip_bfloat16* Bb =
        XPT + (size_t)(GUARD + n0 - SHIFT[tp] + srow) * ICN + kc;
    gload_lds16(Ab,                 &lA[0][wv * 512]);
    gload_lds16(Ab + 64 * ICN,      &lA[0][wv * 512 + 2048]);
    gload_lds16(Ab + 32,            &lA[1][wv * 512]);
    gload_lds16(Ab + 64 * ICN + 32, &lA[1][wv * 512 + 2048]);
    gload_lds16(Bb,                 &lB[0][wv * 512]);
    gload_lds16(Bb + 64 * ICN,      &lB[0][wv * 512 + 2048]);
    gload_lds16(Bb + 32,            &lB[1][wv * 512]);
    gload_lds16(Bb + 64 * ICN + 32, &lB[1][wv * 512 + 2048]);
    __syncthreads();
#pragma unroll
    for (int kk = 0; kk < 2; ++kk) {
      short8 af[4], bfr[4];
#pragma unroll
      for (int m = 0; m < 4; ++m)
        af[m] = *(const short8*)&lA[kk][(wr * 64 + m * 16 + (lane & 15)) * 32 + (lane >> 4) * 8];
#pragma unroll
      for (int n = 0; n < 4; ++n)
        bfr[n] = *(const short8*)&lB[kk][(wc * 64 + n * 16 + (lane & 15)) * 32 + (lane >> 4) * 8];
#pragma unroll
      for (int m = 0; m < 4; ++m)
#pragma unroll
        for (int n = 0; n < 4; ++n)
          acc[m][n] = __builtin_amdgcn_mfma_f32_16x16x32_bf16(af[m], bfr[n], acc[m][n], 0, 0, 0);
    }
    __syncthreads();
  }

  // epilogue: D col = lane&15, row = (lane>>4)*4 + r; mask pad cells to zero
  const int lr = (lane >> 4) * 4, lc = lane & 15;
#pragma unroll
  for (int n = 0; n < 4; ++n) {
    const int col = n0 + wc * 64 + n * 16 + lc;
    const int pa = col / 136, pb = col - pa * 136;
    const bool ok = ((unsigned)(pa - 1) < (unsigned)AR[ph]) &&
                    ((unsigned)(pb - 1) < (unsigned)AC[ph]);
#pragma unroll
    for (int m = 0; m < 4; ++m)
#pragma unroll
      for (int r = 0; r < 4; ++r) {
        const int row = oc0 + wr * 64 + m * 16 + lr + r;
        C[((size_t)(ph * OCN + row)) * NROW + col] =
            __float2bfloat16(ok ? acc[m][n][r] : 0.f);
      }
  }
}

// ---- vectorized depthwise 4x4 blur: 8 outputs/thread, branch-free ----
// Requires C pad cells == 0 (provided by gemm_k's masked epilogue).
struct __align__(8) U4 { unsigned int w[4]; };

__global__ __launch_bounds__(256) void blur2_k(const unsigned short* __restrict__ C,
                                               float* __restrict__ out) {
  const int tid = threadIdx.x;
  const int t  = tid & 31;                  // col block: n in [8t, 8t+8)
  const int m  = blockIdx.x * 8 + (tid >> 5);
  const int oc = blockIdx.y;
  const float cfv[4] = {0.25f, 0.75f, 0.75f, 0.25f};

  float acc[8];
#pragma unroll
  for (int s = 0; s < 8; ++s) acc[s] = 0.f;

#pragma unroll
  for (int i = 0; i < 4; ++i) {
    const int u  = m - 1 + i;
    const int py = u & 1;                   // u=-1 -> 1; u=257 -> 1
    const int r  = (u >> 1) + 1;            // u=-1 -> 0 (zero pad row)
    const size_t base = (size_t)r * 136 + 4 * t;
    const U4 ev = *(const U4*)(C + ((size_t)(py * 2 + 0) * OCN + oc) * NROW + base);
    const U4 ov = *(const U4*)(C + ((size_t)(py * 2 + 1) * OCN + oc) * NROW + base);
    float E[8], O[8];
#pragma unroll
    for (int j = 0; j < 4; ++j) {
      E[2 * j]     = __uint_as_float(ev.w[j] << 16);
      E[2 * j + 1] = __uint_as_float(ev.w[j] & 0xffff0000u);
      O[2 * j]     = __uint_as_float(ov.w[j] << 16);
      O[2 * j + 1] = __uint_as_float(ov.w[j] & 0xffff0000u);
    }
    const float cv = cfv[i];
#pragma unroll
    for (int s = 0; s < 8; ++s) {
      float h;
      if ((s & 1) == 0) {
        const int k = s >> 1;
        h = 0.75f * E[k + 1] + 0.25f * E[k + 2] + 0.25f * O[k] + 0.75f * O[k + 1];
      } else {
        const int k = (s + 1) >> 1;
        h = 0.25f * E[k] + 0.75f * E[k + 1] + 0.75f * O[k] + 0.25f * O[k + 1];
      }
      acc[s] += cv * h;
    }
  }

  float* op = out + ((size_t)oc * 256 + m) * 256 + 8 * t;
  f32x4 s0 = {acc[0], acc[1], acc[2], acc[3]};
  f32x4 s1 = {acc[4], acc[5], acc[6], acc[7]};
  *(f32x4*)op = s0;
  *(f32x4*)(op + 4) = s1;
}

extern "C" void kernel_launch(void* const* d_in, const int* in_sizes, int n_in,
                              void* d_out, int out_size, void* d_ws, size_t ws_size,
                              hipStream_t stream) {
  const float* x = (const float*)d_in[0];
  const float* w = (const float*)d_in[1];
  float* out = (float*)d_out;

  // ws layout (bytes):
  //   AP : 9*512*512*2   = 4,718,592    @ 0
  //   XPT: 17936*512*2   = 18,366,464   @ 4,718,592
  //   C  : 4*512*17792*2 = 72,876,032   @ 23,085,056   (total ~96.0 MB)
  __hip_bfloat16* AP  = (__hip_bfloat16*)d_ws;
  __hip_bfloat16* XPT = (__hip_bfloat16*)((char*)d_ws + 4718592);
  __hip_bfloat16* C   = (__hip_bfloat16*)((char*)d_ws + 23085056);

  wprep_k<<<512, 256, 0, stream>>>(w, AP);
  zguard_k<<<256, 256, 0, stream>>>((unsigned int*)XPT);
  packx2_k<<<dim3(130, 8), 256, 0, stream>>>(x, (unsigned int*)XPT);
  gemm_k<<<dim3(16, NROW / 128), 256, 0, stream>>>(AP, XPT, C);
  blur2_k<<<dim3(32, 512), 256, 0, stream>>>((const unsigned short*)C, out);
}

// Round 9
// 200.630 us; speedup vs baseline: 1.2393x; 1.2393x over previous
//
#include <hip/hip_runtime.h>
#include <hip/hip_bf16.h>

#define ICN 512
#define OCN 512
#define RS    136      // padded pixel-plane row stride (cols)
#define NROW  17792    // GEMM N = 139*128 >= 130*136=17680; also C plane stride
#define GUARD 144      // zero guard rows in front of XPT (max shift 137)
#define XROWS 17936    // GUARD + NROW

typedef __attribute__((ext_vector_type(8))) short short8;
typedef __attribute__((ext_vector_type(4))) float f32x4;

__device__ __forceinline__ void gload_lds16(const void* g, void* l) {
  __builtin_amdgcn_global_load_lds(
      (const __attribute__((address_space(1))) void*)g,
      (__attribute__((address_space(3))) void*)l, 16, 0, 0);
}

// ---- fused demod + weight pack: AP[tp][oc][ic] = coef[oc]*w[oc][ic][widx(tp)] ----
__global__ __launch_bounds__(256) void wprep_k(const float* __restrict__ w,
                                               __hip_bfloat16* __restrict__ AP) {
  constexpr int WIDX[9] = {0, 2, 6, 8, 1, 7, 3, 5, 4};  // tap -> ky*3+kx
  const int oc = blockIdx.x;
  const int tid = threadIdx.x, lane = tid & 63, wv = tid >> 6;

  float v[2][9];
  float s = 0.f;
#pragma unroll
  for (int rep = 0; rep < 2; ++rep) {
    const int ic = tid + rep * 256;
    const float* wp = w + ((size_t)oc * ICN + ic) * 9;
#pragma unroll
    for (int j = 0; j < 9; ++j) { v[rep][j] = wp[j]; s += wp[j] * wp[j]; }
  }
#pragma unroll
  for (int o = 32; o > 0; o >>= 1) s += __shfl_down(s, o, 64);
  __shared__ float red[4];
  if (lane == 0) red[wv] = s;
  __syncthreads();
  const float tot = red[0] + red[1] + red[2] + red[3];
  const float scale2 = 1.0f / 4608.0f;
  const float c = sqrtf(scale2) * rsqrtf(scale2 * tot + 1e-8f);

#pragma unroll
  for (int rep = 0; rep < 2; ++rep) {
    const int ic = tid + rep * 256;
#pragma unroll
    for (int tp = 0; tp < 9; ++tp)
      AP[((size_t)tp * OCN + oc) * ICN + ic] = __float2bfloat16(c * v[rep][WIDX[tp]]);
  }
}

// ---- x -> bf16 transposed padded pixel space, via LDS transpose tile ----
// XPT[row][ic], row = GUARD + py*136 + px; valid pixels px-1,py-1 in [0,128)
__global__ __launch_bounds__(256) void packx2_k(const float* __restrict__ x,
                                                unsigned int* __restrict__ XP32) {
  const int py  = blockIdx.x;        // 0..129
  const int ic0 = blockIdx.y * 64;
  const int tid = threadIdx.x;
  const int yy  = py - 1;
  const bool rowvalid = (unsigned)yy < 128u;

  __shared__ __hip_bfloat16 T[128 * 65];   // T[xx][ic_i], padded stride 65

  if (rowvalid) {
    const float4* xr = (const float4*)(x + (size_t)ic0 * 16384 + (size_t)yy * 128);
#pragma unroll
    for (int rep = 0; rep < 8; ++rep) {
      const int idx = rep * 256 + tid;     // 0..2047
      const int x4 = idx & 31, ici = idx >> 5;
      const float4 v = xr[(size_t)ici * 4096 + x4];   // coalesced 16B/lane
      const int xx = x4 * 4;
      T[(xx + 0) * 65 + ici] = __float2bfloat16(v.x);
      T[(xx + 1) * 65 + ici] = __float2bfloat16(v.y);
      T[(xx + 2) * 65 + ici] = __float2bfloat16(v.z);
      T[(xx + 3) * 65 + ici] = __float2bfloat16(v.w);
    }
  }
  __syncthreads();

  const size_t rowbase = (size_t)(GUARD + py * 136) * 256 + (ic0 >> 1);
  // 136 px-rows * 32 u32 = 4352 words; 17 reps of 256
  for (int rep = 0; rep < 17; ++rep) {
    const int idx = rep * 256 + tid;
    const int px = idx >> 5, j = idx & 31;
    unsigned int uv = 0;
    if (rowvalid && (unsigned)(px - 1) < 128u) {
      union { __hip_bfloat16 h[2]; unsigned int u; } cv;
      cv.h[0] = T[(px - 1) * 65 + 2 * j];
      cv.h[1] = T[(px - 1) * 65 + 2 * j + 1];
      uv = cv.u;
    }
    XP32[rowbase + (size_t)px * 256 + j] = uv;   // coalesced 128B/half-wave
  }
}

// ---- zero the guard rows [0,144) and tail rows [17824,17936) of XPT ----
__global__ __launch_bounds__(256) void zguard_k(unsigned int* __restrict__ XP32) {
  const int r = blockIdx.x;                       // 0..255
  const int row = (r < 144) ? r : (r + 17680);    // 144->17824 .. 255->17935
  XP32[(size_t)row * 256 + threadIdx.x] = 0;
}

// ---- MFMA implicit GEMM: C[ph][oc][n] = sum_t sum_ic AP[tp][oc][ic]*XPT[n-sh][ic]
// R7 internals (BK=32, per-tap loop). XCD-aware grid: the 16 (oc,ph) blocks of
// one n-tile sit 8 apart in dispatch order -> same XCD -> B-tile fetched into
// that XCD's L2 once; the 8 XCDs stream 8 different n-tiles (MLP preserved).
// Epilogue writes 0 to pixel-space pad cells so the blur can read branch-free.
__global__ __launch_bounds__(256) void gemm_k(const __hip_bfloat16* __restrict__ AP,
                                              const __hip_bfloat16* __restrict__ XPT,
                                              __hip_bfloat16* __restrict__ C) {
  constexpr int NTt[4]   = {4, 2, 2, 1};
  constexpr int TPO[4]   = {0, 4, 6, 8};
  constexpr int SHIFT[9] = {0, 1, 136, 137, 0, 136, 0, 1, 0};
  constexpr int AR[4]    = {129, 129, 128, 128};  // valid pixel rows per phase
  constexpr int AC[4]    = {129, 128, 129, 128};  // valid pixel cols per phase

  const int g   = blockIdx.x;
  const int xcd = g & 7;
  const int s   = g >> 3;                  // 0..287
  const int nt  = xcd + 8 * (s >> 4);      // n-tile, round-robin per XCD
  if (nt >= 139) return;
  const int ocph = s & 15;
  const int ph   = ocph & 3;
  const int oc0  = (ocph >> 2) * 128;
  const int n0   = nt * 128;

  const int tid = threadIdx.x, lane = tid & 63, wv = tid >> 6;
  const int wr = wv >> 1, wc = wv & 1;

  __shared__ __align__(16) __hip_bfloat16 lA[128 * 32];
  __shared__ __align__(16) __hip_bfloat16 lB[128 * 32];

  const int srow = tid >> 2;          // 0..63 (staging row)
  const int scol = (tid & 3) * 8;     // staging col (elems)
  __hip_bfloat16* ldA0 = &lA[wv * 512];
  __hip_bfloat16* ldA1 = &lA[wv * 512 + 2048];
  __hip_bfloat16* ldB0 = &lB[wv * 512];
  __hip_bfloat16* ldB1 = &lB[wv * 512 + 2048];

  f32x4 acc[4][4];
#pragma unroll
  for (int m = 0; m < 4; ++m)
#pragma unroll
    for (int n = 0; n < 4; ++n) acc[m][n] = (f32x4){0.f, 0.f, 0.f, 0.f};

  const int ntaps = NTt[ph];
  for (int t = 0; t < ntaps; ++t) {
    const int tp = TPO[ph] + t;
    const __hip_bfloat16* Ab = AP + (size_t)tp * (ICN * OCN) + (size_t)oc0 * ICN;
    const __hip_bfloat16* Bb = XPT + (size_t)(GUARD + n0 - SHIFT[tp]) * ICN;
    for (int ks = 0; ks < 16; ++ks) {
      const int kc = ks * 32 + scol;
      gload_lds16(Ab + (size_t)srow * ICN + kc, ldA0);
      gload_lds16(Ab + (size_t)(srow + 64) * ICN + kc, ldA1);
      gload_lds16(Bb + (size_t)srow * ICN + kc, ldB0);
      gload_lds16(Bb + (size_t)(srow + 64) * ICN + kc, ldB1);
      __syncthreads();
      short8 af[4], bfr[4];
#pragma unroll
      for (int m = 0; m < 4; ++m)
        af[m] = *(const short8*)&lA[(wr * 64 + m * 16 + (lane & 15)) * 32 + (lane >> 4) * 8];
#pragma unroll
      for (int n = 0; n < 4; ++n)
        bfr[n] = *(const short8*)&lB[(wc * 64 + n * 16 + (lane & 15)) * 32 + (lane >> 4) * 8];
#pragma unroll
      for (int m = 0; m < 4; ++m)
#pragma unroll
        for (int n = 0; n < 4; ++n)
          acc[m][n] = __builtin_amdgcn_mfma_f32_16x16x32_bf16(af[m], bfr[n], acc[m][n], 0, 0, 0);
      __syncthreads();
    }
  }

  // epilogue: D col = lane&15, row = (lane>>4)*4 + r; mask pad cells to zero
  const int lr = (lane >> 4) * 4, lc = lane & 15;
#pragma unroll
  for (int n = 0; n < 4; ++n) {
    const int col = n0 + wc * 64 + n * 16 + lc;
    const int pa = col / 136, pb = col - pa * 136;
    const bool ok = ((unsigned)(pa - 1) < (unsigned)AR[ph]) &&
                    ((unsigned)(pb - 1) < (unsigned)AC[ph]);
#pragma unroll
    for (int m = 0; m < 4; ++m)
#pragma unroll
      for (int r = 0; r < 4; ++r) {
        const int row = oc0 + wr * 64 + m * 16 + lr + r;
        C[((size_t)(ph * OCN + row)) * NROW + col] =
            __float2bfloat16(ok ? acc[m][n][r] : 0.f);
      }
  }
}

// ---- vectorized depthwise 4x4 blur: 8 outputs/thread, branch-free ----
// Requires C pad cells == 0 (provided by gemm_k's masked epilogue).
struct __align__(8) U4 { unsigned int w[4]; };

__global__ __launch_bounds__(256) void blur2_k(const unsigned short* __restrict__ C,
                                               float* __restrict__ out) {
  const int tid = threadIdx.x;
  const int t  = tid & 31;                  // col block: n in [8t, 8t+8)
  const int m  = blockIdx.x * 8 + (tid >> 5);
  const int oc = blockIdx.y;
  const float cfv[4] = {0.25f, 0.75f, 0.75f, 0.25f};

  float acc[8];
#pragma unroll
  for (int s = 0; s < 8; ++s) acc[s] = 0.f;

#pragma unroll
  for (int i = 0; i < 4; ++i) {
    const int u  = m - 1 + i;
    const int py = u & 1;                   // u=-1 -> 1; u=257 -> 1
    const int r  = (u >> 1) + 1;            // u=-1 -> 0 (zero pad row)
    const size_t base = (size_t)r * 136 + 4 * t;
    const U4 ev = *(const U4*)(C + ((size_t)(py * 2 + 0) * OCN + oc) * NROW + base);
    const U4 ov = *(const U4*)(C + ((size_t)(py * 2 + 1) * OCN + oc) * NROW + base);
    float E[8], O[8];
#pragma unroll
    for (int j = 0; j < 4; ++j) {
      E[2 * j]     = __uint_as_float(ev.w[j] << 16);
      E[2 * j + 1] = __uint_as_float(ev.w[j] & 0xffff0000u);
      O[2 * j]     = __uint_as_float(ov.w[j] << 16);
      O[2 * j + 1] = __uint_as_float(ov.w[j] & 0xffff0000u);
    }
    const float cv = cfv[i];
#pragma unroll
    for (int s = 0; s < 8; ++s) {
      float h;
      if ((s & 1) == 0) {
        const int k = s >> 1;
        h = 0.75f * E[k + 1] + 0.25f * E[k + 2] + 0.25f * O[k] + 0.75f * O[k + 1];
      } else {
        const int k = (s + 1) >> 1;
        h = 0.25f * E[k] + 0.75f * E[k + 1] + 0.75f * O[k] + 0.25f * O[k + 1];
      }
      acc[s] += cv * h;
    }
  }

  float* op = out + ((size_t)oc * 256 + m) * 256 + 8 * t;
  f32x4 s0 = {acc[0], acc[1], acc[2], acc[3]};
  f32x4 s1 = {acc[4], acc[5], acc[6], acc[7]};
  *(f32x4*)op = s0;
  *(f32x4*)(op + 4) = s1;
}

extern "C" void kernel_launch(void* const* d_in, const int* in_sizes, int n_in,
                              void* d_out, int out_size, void* d_ws, size_t ws_size,
                              hipStream_t stream) {
  const float* x = (const float*)d_in[0];
  const float* w = (const float*)d_in[1];
  float* out = (float*)d_out;

  // ws layout (bytes):
  //   AP : 9*512*512*2   = 4,718,592    @ 0
  //   XPT: 17936*512*2   = 18,366,464   @ 4,718,592
  //   C  : 4*512*17792*2 = 72,876,032   @ 23,085,056   (total ~96.0 MB)
  __hip_bfloat16* AP  = (__hip_bfloat16*)d_ws;
  __hip_bfloat16* XPT = (__hip_bfloat16*)((char*)d_ws + 4718592);
  __hip_bfloat16* C   = (__hip_bfloat16*)((char*)d_ws + 23085056);

  wprep_k<<<512, 256, 0, stream>>>(w, AP);
  zguard_k<<<256, 256, 0, stream>>>((unsigned int*)XPT);
  packx2_k<<<dim3(130, 8), 256, 0, stream>>>(x, (unsigned int*)XPT);
  gemm_k<<<8 * 18 * 16, 256, 0, stream>>>(AP, XPT, C);
  blur2_k<<<dim3(32, 512), 256, 0, stream>>>((const unsigned short*)C, out);
}

// Round 10
// 174.549 us; speedup vs baseline: 1.4245x; 1.1494x over previous
//
#include <hip/hip_runtime.h>
#include <hip/hip_bf16.h>

#define ICN 512
#define OCN 512
#define RS    136      // padded pixel-plane row stride (cols)
#define NROW  17792    // GEMM N = 139*128 >= 130*136=17680; also C plane stride
#define GUARD 144      // zero guard rows in front of XPT (max shift 137)
#define XROWS 17936    // GUARD + NROW

typedef __attribute__((ext_vector_type(8))) short short8;
typedef __attribute__((ext_vector_type(4))) float f32x4;

__device__ __forceinline__ void gload_lds16(const void* g, void* l) {
  __builtin_amdgcn_global_load_lds(
      (const __attribute__((address_space(1))) void*)g,
      (__attribute__((address_space(3))) void*)l, 16, 0, 0);
}

// ---- fused demod + weight pack: AP[tp][oc][ic] = coef[oc]*w[oc][ic][widx(tp)] ----
__global__ __launch_bounds__(256) void wprep_k(const float* __restrict__ w,
                                               __hip_bfloat16* __restrict__ AP) {
  constexpr int WIDX[9] = {0, 2, 6, 8, 1, 7, 3, 5, 4};  // tap -> ky*3+kx
  const int oc = blockIdx.x;
  const int tid = threadIdx.x, lane = tid & 63, wv = tid >> 6;

  float v[2][9];
  float s = 0.f;
#pragma unroll
  for (int rep = 0; rep < 2; ++rep) {
    const int ic = tid + rep * 256;
    const float* wp = w + ((size_t)oc * ICN + ic) * 9;
#pragma unroll
    for (int j = 0; j < 9; ++j) { v[rep][j] = wp[j]; s += wp[j] * wp[j]; }
  }
#pragma unroll
  for (int o = 32; o > 0; o >>= 1) s += __shfl_down(s, o, 64);
  __shared__ float red[4];
  if (lane == 0) red[wv] = s;
  __syncthreads();
  const float tot = red[0] + red[1] + red[2] + red[3];
  const float scale2 = 1.0f / 4608.0f;
  const float c = sqrtf(scale2) * rsqrtf(scale2 * tot + 1e-8f);

#pragma unroll
  for (int rep = 0; rep < 2; ++rep) {
    const int ic = tid + rep * 256;
#pragma unroll
    for (int tp = 0; tp < 9; ++tp)
      AP[((size_t)tp * OCN + oc) * ICN + ic] = __float2bfloat16(c * v[rep][WIDX[tp]]);
  }
}

// ---- x -> bf16 transposed padded pixel space, via LDS transpose tile ----
// XPT[row][ic], row = GUARD + py*136 + px; valid pixels px-1,py-1 in [0,128)
__global__ __launch_bounds__(256) void packx2_k(const float* __restrict__ x,
                                                unsigned int* __restrict__ XP32) {
  const int py  = blockIdx.x;        // 0..129
  const int ic0 = blockIdx.y * 64;
  const int tid = threadIdx.x;
  const int yy  = py - 1;
  const bool rowvalid = (unsigned)yy < 128u;

  __shared__ __hip_bfloat16 T[128 * 65];   // T[xx][ic_i], padded stride 65

  if (rowvalid) {
    const float4* xr = (const float4*)(x + (size_t)ic0 * 16384 + (size_t)yy * 128);
#pragma unroll
    for (int rep = 0; rep < 8; ++rep) {
      const int idx = rep * 256 + tid;     // 0..2047
      const int x4 = idx & 31, ici = idx >> 5;
      const float4 v = xr[(size_t)ici * 4096 + x4];   // coalesced 16B/lane
      const int xx = x4 * 4;
      T[(xx + 0) * 65 + ici] = __float2bfloat16(v.x);
      T[(xx + 1) * 65 + ici] = __float2bfloat16(v.y);
      T[(xx + 2) * 65 + ici] = __float2bfloat16(v.z);
      T[(xx + 3) * 65 + ici] = __float2bfloat16(v.w);
    }
  }
  __syncthreads();

  const size_t rowbase = (size_t)(GUARD + py * 136) * 256 + (ic0 >> 1);
  // 136 px-rows * 32 u32 = 4352 words; 17 reps of 256
  for (int rep = 0; rep < 17; ++rep) {
    const int idx = rep * 256 + tid;
    const int px = idx >> 5, j = idx & 31;
    unsigned int uv = 0;
    if (rowvalid && (unsigned)(px - 1) < 128u) {
      union { __hip_bfloat16 h[2]; unsigned int u; } cv;
      cv.h[0] = T[(px - 1) * 65 + 2 * j];
      cv.h[1] = T[(px - 1) * 65 + 2 * j + 1];
      uv = cv.u;
    }
    XP32[rowbase + (size_t)px * 256 + j] = uv;   // coalesced 128B/half-wave
  }
}

// ---- zero the guard rows [0,144) and tail rows [17824,17936) of XPT ----
__global__ __launch_bounds__(256) void zguard_k(unsigned int* __restrict__ XP32) {
  const int r = blockIdx.x;                       // 0..255
  const int row = (r < 144) ? r : (r + 17680);    // 144->17824 .. 255->17935
  XP32[(size_t)row * 256 + threadIdx.x] = 0;
}

// ---- MFMA implicit GEMM, 2-phase double-buffered prefetch ----
// C[ph][oc][n] = sum_t sum_ic AP[tp][oc][ic]*XPT[n-sh][ic]
// Per K-step: STAGE(next -> buf^1) issued BEFORE compute(cur); single
// __syncthreads() per step (drains vmcnt for the prefetch + lgkm for reads).
// Epilogue writes 0 to pixel-space pad cells so the blur can read branch-free.
__global__ __launch_bounds__(256) void gemm_k(const __hip_bfloat16* __restrict__ AP,
                                              const __hip_bfloat16* __restrict__ XPT,
                                              __hip_bfloat16* __restrict__ C) {
  constexpr int NTt[4]   = {4, 2, 2, 1};
  constexpr int TPO[4]   = {0, 4, 6, 8};
  constexpr int SHIFT[9] = {0, 1, 136, 137, 0, 136, 0, 1, 0};
  constexpr int AR[4]    = {129, 129, 128, 128};  // valid pixel rows per phase
  constexpr int AC[4]    = {129, 128, 129, 128};  // valid pixel cols per phase

  const int n0 = blockIdx.x * 128, oc0 = blockIdx.y * 128, ph = blockIdx.z;
  const int tid = threadIdx.x, lane = tid & 63, wv = tid >> 6;
  const int wr = wv >> 1, wc = wv & 1;

  __shared__ __align__(16) __hip_bfloat16 lA[2][128 * 32];
  __shared__ __align__(16) __hip_bfloat16 lB[2][128 * 32];

  const int srow = tid >> 2;          // 0..63 (staging row)
  const int scol = (tid & 3) * 8;     // staging col (elems)

  auto stage = [&](int i, int buf) {
    const int tp = TPO[ph] + (i >> 4);
    const int kc = (i & 15) * 32 + scol;
    const __hip_bfloat16* Ab =
        AP + (size_t)tp * (ICN * OCN) + (size_t)(oc0 + srow) * ICN + kc;
    const __hip_bfloat16* Bb =
        XPT + (size_t)(GUARD + n0 - SHIFT[tp] + srow) * ICN + kc;
    gload_lds16(Ab,            &lA[buf][wv * 512]);
    gload_lds16(Ab + 64 * ICN, &lA[buf][wv * 512 + 2048]);
    gload_lds16(Bb,            &lB[buf][wv * 512]);
    gload_lds16(Bb + 64 * ICN, &lB[buf][wv * 512 + 2048]);
  };

  f32x4 acc[4][4];
#pragma unroll
  for (int m = 0; m < 4; ++m)
#pragma unroll
    for (int n = 0; n < 4; ++n) acc[m][n] = (f32x4){0.f, 0.f, 0.f, 0.f};

  const int total = NTt[ph] * 16;     // 32-wide K-chunks across all taps
  stage(0, 0);
  __syncthreads();
  int cur = 0;
  for (int i = 0; i < total; ++i) {
    if (i + 1 < total) stage(i + 1, cur ^ 1);   // prefetch hides under compute
    short8 af[4], bfr[4];
#pragma unroll
    for (int m = 0; m < 4; ++m)
      af[m] = *(const short8*)&lA[cur][(wr * 64 + m * 16 + (lane & 15)) * 32 + (lane >> 4) * 8];
#pragma unroll
    for (int n = 0; n < 4; ++n)
      bfr[n] = *(const short8*)&lB[cur][(wc * 64 + n * 16 + (lane & 15)) * 32 + (lane >> 4) * 8];
#pragma unroll
    for (int m = 0; m < 4; ++m)
#pragma unroll
      for (int n = 0; n < 4; ++n)
        acc[m][n] = __builtin_amdgcn_mfma_f32_16x16x32_bf16(af[m], bfr[n], acc[m][n], 0, 0, 0);
    __syncthreads();                            // drains prefetch vmcnt + read lgkm
    cur ^= 1;
  }

  // epilogue: D col = lane&15, row = (lane>>4)*4 + r; mask pad cells to zero
  const int lr = (lane >> 4) * 4, lc = lane & 15;
#pragma unroll
  for (int n = 0; n < 4; ++n) {
    const int col = n0 + wc * 64 + n * 16 + lc;
    const int pa = col / 136, pb = col - pa * 136;
    const bool ok = ((unsigned)(pa - 1) < (unsigned)AR[ph]) &&
                    ((unsigned)(pb - 1) < (unsigned)AC[ph]);
#pragma unroll
    for (int m = 0; m < 4; ++m)
#pragma unroll
      for (int r = 0; r < 4; ++r) {
        const int row = oc0 + wr * 64 + m * 16 + lr + r;
        C[((size_t)(ph * OCN + row)) * NROW + col] =
            __float2bfloat16(ok ? acc[m][n][r] : 0.f);
      }
  }
}

// ---- vectorized depthwise 4x4 blur: 8 outputs/thread, branch-free ----
// Requires C pad cells == 0 (provided by gemm_k's masked epilogue).
struct __align__(8) U4 { unsigned int w[4]; };

__global__ __launch_bounds__(256) void blur2_k(const unsigned short* __restrict__ C,
                                               float* __restrict__ out) {
  const int tid = threadIdx.x;
  const int t  = tid & 31;                  // col block: n in [8t, 8t+8)
  const int m  = blockIdx.x * 8 + (tid >> 5);
  const int oc = blockIdx.y;
  const float cfv[4] = {0.25f, 0.75f, 0.75f, 0.25f};

  float acc[8];
#pragma unroll
  for (int s = 0; s < 8; ++s) acc[s] = 0.f;

#pragma unroll
  for (int i = 0; i < 4; ++i) {
    const int u  = m - 1 + i;
    const int py = u & 1;                   // u=-1 -> 1; u=257 -> 1
    const int r  = (u >> 1) + 1;            // u=-1 -> 0 (zero pad row)
    const size_t base = (size_t)r * 136 + 4 * t;
    const U4 ev = *(const U4*)(C + ((size_t)(py * 2 + 0) * OCN + oc) * NROW + base);
    const U4 ov = *(const U4*)(C + ((size_t)(py * 2 + 1) * OCN + oc) * NROW + base);
    float E[8], O[8];
#pragma unroll
    for (int j = 0; j < 4; ++j) {
      E[2 * j]     = __uint_as_float(ev.w[j] << 16);
      E[2 * j + 1] = __uint_as_float(ev.w[j] & 0xffff0000u);
      O[2 * j]     = __uint_as_float(ov.w[j] << 16);
      O[2 * j + 1] = __uint_as_float(ov.w[j] & 0xffff0000u);
    }
    const float cv = cfv[i];
#pragma unroll
    for (int s = 0; s < 8; ++s) {
      float h;
      if ((s & 1) == 0) {
        const int k = s >> 1;
        h = 0.75f * E[k + 1] + 0.25f * E[k + 2] + 0.25f * O[k] + 0.75f * O[k + 1];
      } else {
        const int k = (s + 1) >> 1;
        h = 0.25f * E[k] + 0.75f * E[k + 1] + 0.75f * O[k] + 0.25f * O[k + 1];
      }
      acc[s] += cv * h;
    }
  }

  float* op = out + ((size_t)oc * 256 + m) * 256 + 8 * t;
  f32x4 s0 = {acc[0], acc[1], acc[2], acc[3]};
  f32x4 s1 = {acc[4], acc[5], acc[6], acc[7]};
  *(f32x4*)op = s0;
  *(f32x4*)(op + 4) = s1;
}

extern "C" void kernel_launch(void* const* d_in, const int* in_sizes, int n_in,
                              void* d_out, int out_size, void* d_ws, size_t ws_size,
                              hipStream_t stream) {
  const float* x = (const float*)d_in[0];
  const float* w = (const float*)d_in[1];
  float* out = (float*)d_out;

  // ws layout (bytes):
  //   AP : 9*512*512*2   = 4,718,592    @ 0
  //   XPT: 17936*512*2   = 18,366,464   @ 4,718,592
  //   C  : 4*512*17792*2 = 72,876,032   @ 23,085,056   (total ~96.0 MB)
  __hip_bfloat16* AP  = (__hip_bfloat16*)d_ws;
  __hip_bfloat16* XPT = (__hip_bfloat16*)((char*)d_ws + 4718592);
  __hip_bfloat16* C   = (__hip_bfloat16*)((char*)d_ws + 23085056);

  wprep_k<<<512, 256, 0, stream>>>(w, AP);
  zguard_k<<<256, 256, 0, stream>>>((unsigned int*)XPT);
  packx2_k<<<dim3(130, 8), 256, 0, stream>>>(x, (unsigned int*)XPT);
  gemm_k<<<dim3(NROW / 128, 4, 4), 256, 0, stream>>>(AP, XPT, C);
  blur2_k<<<dim3(32, 512), 256, 0, stream>>>((const unsigned short*)C, out);
}

// Round 11
// 165.022 us; speedup vs baseline: 1.5068x; 1.0577x over previous
//
#include <hip/hip_runtime.h>
#include <hip/hip_bf16.h>

#define ICN 512
#define OCN 512
#define RS    136      // padded pixel-plane row stride (cols)
#define NROW  17792    // GEMM N cols = 139*128; C plane stride
#define GUARD 144      // zero guard rows in front of XPT (max shift 137)
#define XROWS 17936    // GUARD + NROW

typedef __attribute__((ext_vector_type(8))) short short8;
typedef __attribute__((ext_vector_type(4))) float f32x4;

__device__ __forceinline__ void gload_lds16(const void* g, void* l) {
  __builtin_amdgcn_global_load_lds(
      (const __attribute__((address_space(1))) void*)g,
      (__attribute__((address_space(3))) void*)l, 16, 0, 0);
}

// raw barrier: execution sync WITHOUT vmcnt drain; compiler fences pin LDS ops
__device__ __forceinline__ void bar_raw() {
  asm volatile("" ::: "memory");
  __builtin_amdgcn_s_barrier();
  asm volatile("" ::: "memory");
}

// ---- fused demod + weight pack: AP[tp][oc][ic] = coef[oc]*w[oc][ic][widx(tp)] ----
__global__ __launch_bounds__(256) void wprep_k(const float* __restrict__ w,
                                               __hip_bfloat16* __restrict__ AP) {
  constexpr int WIDX[9] = {0, 2, 6, 8, 1, 7, 3, 5, 4};  // tap -> ky*3+kx
  const int oc = blockIdx.x;
  const int tid = threadIdx.x, lane = tid & 63, wv = tid >> 6;

  float v[2][9];
  float s = 0.f;
#pragma unroll
  for (int rep = 0; rep < 2; ++rep) {
    const int ic = tid + rep * 256;
    const float* wp = w + ((size_t)oc * ICN + ic) * 9;
#pragma unroll
    for (int j = 0; j < 9; ++j) { v[rep][j] = wp[j]; s += wp[j] * wp[j]; }
  }
#pragma unroll
  for (int o = 32; o > 0; o >>= 1) s += __shfl_down(s, o, 64);
  __shared__ float red[4];
  if (lane == 0) red[wv] = s;
  __syncthreads();
  const float tot = red[0] + red[1] + red[2] + red[3];
  const float scale2 = 1.0f / 4608.0f;
  const float c = sqrtf(scale2) * rsqrtf(scale2 * tot + 1e-8f);

#pragma unroll
  for (int rep = 0; rep < 2; ++rep) {
    const int ic = tid + rep * 256;
#pragma unroll
    for (int tp = 0; tp < 9; ++tp)
      AP[((size_t)tp * OCN + oc) * ICN + ic] = __float2bfloat16(c * v[rep][WIDX[tp]]);
  }
}

// ---- x -> bf16 transposed padded pixel space, via LDS transpose tile ----
__global__ __launch_bounds__(256) void packx2_k(const float* __restrict__ x,
                                                unsigned int* __restrict__ XP32) {
  const int py  = blockIdx.x;        // 0..129
  const int ic0 = blockIdx.y * 64;
  const int tid = threadIdx.x;
  const int yy  = py - 1;
  const bool rowvalid = (unsigned)yy < 128u;

  __shared__ __hip_bfloat16 T[128 * 65];   // T[xx][ic_i], padded stride 65

  if (rowvalid) {
    const float4* xr = (const float4*)(x + (size_t)ic0 * 16384 + (size_t)yy * 128);
#pragma unroll
    for (int rep = 0; rep < 8; ++rep) {
      const int idx = rep * 256 + tid;     // 0..2047
      const int x4 = idx & 31, ici = idx >> 5;
      const float4 v = xr[(size_t)ici * 4096 + x4];   // coalesced 16B/lane
      const int xx = x4 * 4;
      T[(xx + 0) * 65 + ici] = __float2bfloat16(v.x);
      T[(xx + 1) * 65 + ici] = __float2bfloat16(v.y);
      T[(xx + 2) * 65 + ici] = __float2bfloat16(v.z);
      T[(xx + 3) * 65 + ici] = __float2bfloat16(v.w);
    }
  }
  __syncthreads();

  const size_t rowbase = (size_t)(GUARD + py * 136) * 256 + (ic0 >> 1);
  for (int rep = 0; rep < 17; ++rep) {
    const int idx = rep * 256 + tid;
    const int px = idx >> 5, j = idx & 31;
    unsigned int uv = 0;
    if (rowvalid && (unsigned)(px - 1) < 128u) {
      union { __hip_bfloat16 h[2]; unsigned int u; } cv;
      cv.h[0] = T[(px - 1) * 65 + 2 * j];
      cv.h[1] = T[(px - 1) * 65 + 2 * j + 1];
      uv = cv.u;
    }
    XP32[rowbase + (size_t)px * 256 + j] = uv;   // coalesced
  }
}

// ---- zero the guard rows [0,144) and tail rows [17824,17936) of XPT ----
__global__ __launch_bounds__(256) void zguard_k(unsigned int* __restrict__ XP32) {
  const int r = blockIdx.x;                       // 0..255
  const int row = (r < 144) ? r : (r + 17680);    // 144->17824 .. 255->17935
  XP32[(size_t)row * 256 + threadIdx.x] = 0;
}

// ---- MFMA implicit GEMM, 256x256 tile, 3-deep counted-vmcnt pipeline ----
// C[ph][oc][n] = sum_t sum_ic AP[tp][oc][ic]*XPT[n-sh][ic]
// 8 waves (2M x 4N), per-wave 128x64. BK=32. 3 LDS buffers (96 KB) rotate;
// stage of tile t+2 issued at iter t; vmcnt(8) (counted, never 0) + raw
// s_barrier is the cross-wave handshake (loads stay in flight across it).
// LDS swizzle off^=((off>>6)&3)<<4 applied BOTH sides (pre-swz global source,
// swz ds_read) -- involution on 16B chunks.
__global__ __launch_bounds__(512, 2) void gemm_k(const __hip_bfloat16* __restrict__ AP,
                                                 const __hip_bfloat16* __restrict__ XPT,
                                                 __hip_bfloat16* __restrict__ C) {
  constexpr int NTt[4]   = {4, 2, 2, 1};
  constexpr int TPO[4]   = {0, 4, 6, 8};
  constexpr int SHIFT[9] = {0, 1, 136, 137, 0, 136, 0, 1, 0};
  constexpr int AR[4]    = {129, 129, 128, 128};  // valid pixel rows per phase
  constexpr int AC[4]    = {129, 128, 129, 128};  // valid pixel cols per phase

  const int n0 = blockIdx.x * 256, oc0 = blockIdx.y * 256, ph = blockIdx.z;
  const int tid = threadIdx.x, lane = tid & 63, wv = tid >> 6;
  const int wr = wv >> 2, wc = wv & 3;            // 2M x 4N wave grid
  const int klane = (lane >> 4) * 16;             // K byte-offset of lane's chunk

  __shared__ __align__(16) char lds[3 * 32768];   // [buf][A 16KB | B 16KB]

  const int T = NTt[ph] * 16;                     // K-tiles of 32

  // stage tile ts (4 gload ops: A0,A1,B0,B1) into buffer buf
  auto STAGE = [&](int ts, int buf) {
    const int tp = TPO[ph] + (ts >> 4);
    const size_t kt64 = (size_t)(ts & 15) * 64;   // K byte offset in 1024B row
    const char* Ab = (const char*)AP + (size_t)tp * (512 * 1024) +
                     (size_t)oc0 * 1024 + kt64;
    const char* Bb = (const char*)XPT +
                     (size_t)(GUARD + n0 - SHIFT[tp]) * 1024 + kt64;
    char* L = lds + buf * 32768;
#pragma unroll
    for (int o = 0; o < 2; ++o) {
      const int d = o * 8192 + tid * 16;          // linear dest in 16KB tile
      const int s = d ^ (((d >> 6) & 3) << 4);    // pre-swizzled source
      gload_lds16(Ab + (s >> 6) * 1024 + (s & 63), L + o * 8192 + wv * 1024);
    }
#pragma unroll
    for (int o = 0; o < 2; ++o) {
      const int d = o * 8192 + tid * 16;
      const int s = d ^ (((d >> 6) & 3) << 4);
      gload_lds16(Bb + (s >> 6) * 1024 + (s & 63),
                  L + 16384 + o * 8192 + wv * 1024);
    }
  };

  f32x4 acc[8][4];
#pragma unroll
  for (int m = 0; m < 8; ++m)
#pragma unroll
    for (int n = 0; n < 4; ++n) acc[m][n] = (f32x4){0.f, 0.f, 0.f, 0.f};

  STAGE(0, 0);
  STAGE(1, 1);

  for (int t = 0; t < T; ++t) {
    const int ts = (t + 2 < T) ? (t + 2) : (T - 1);   // tail: dummy re-stage
    STAGE(ts, (t + 2) % 3);
    asm volatile("s_waitcnt vmcnt(8)" ::: "memory");  // own slice of tile t landed
    __builtin_amdgcn_sched_barrier(0);
    bar_raw();                                        // all waves' slices landed

    const char* LA = lds + (t % 3) * 32768;
    const char* LB = LA + 16384;
    short8 bf[4], af[8];
#pragma unroll
    for (int n = 0; n < 4; ++n) {
      const int b = (wc * 64 + n * 16 + (lane & 15)) * 64 + klane;
      bf[n] = *(const short8*)(LB + (b ^ (((b >> 6) & 3) << 4)));
    }
#pragma unroll
    for (int m = 0; m < 8; ++m) {
      const int a = (wr * 128 + m * 16 + (lane & 15)) * 64 + klane;
      af[m] = *(const short8*)(LA + (a ^ (((a >> 6) & 3) << 4)));
    }
    asm volatile("s_waitcnt lgkmcnt(4)");             // bf0-3 + af0-3 landed
    __builtin_amdgcn_sched_barrier(0);
    __builtin_amdgcn_s_setprio(1);
#pragma unroll
    for (int m = 0; m < 4; ++m)
#pragma unroll
      for (int n = 0; n < 4; ++n)
        acc[m][n] = __builtin_amdgcn_mfma_f32_16x16x32_bf16(af[m], bf[n], acc[m][n], 0, 0, 0);
    asm volatile("s_waitcnt lgkmcnt(0)");
    __builtin_amdgcn_sched_barrier(0);
#pragma unroll
    for (int m = 4; m < 8; ++m)
#pragma unroll
      for (int n = 0; n < 4; ++n)
        acc[m][n] = __builtin_amdgcn_mfma_f32_16x16x32_bf16(af[m], bf[n], acc[m][n], 0, 0, 0);
    __builtin_amdgcn_s_setprio(0);
    asm volatile("s_waitcnt lgkmcnt(0)" ::: "memory"); // reads done before others re-stage
    bar_raw();
  }

  // epilogue: D col = lane&15, row = (lane>>4)*4 + r; mask pad cells to zero
  const int lr = (lane >> 4) * 4, lc = lane & 15;
#pragma unroll
  for (int n = 0; n < 4; ++n) {
    const int col = n0 + wc * 64 + n * 16 + lc;
    if (col < NROW) {
      const int pa = col / 136, pb = col - pa * 136;
      const bool ok = ((unsigned)(pa - 1) < (unsigned)AR[ph]) &&
                      ((unsigned)(pb - 1) < (unsigned)AC[ph]);
#pragma unroll
      for (int m = 0; m < 8; ++m)
#pragma unroll
        for (int r = 0; r < 4; ++r) {
          const int row = oc0 + wr * 128 + m * 16 + lr + r;
          C[((size_t)(ph * OCN + row)) * NROW + col] =
              __float2bfloat16(ok ? acc[m][n][r] : 0.f);
        }
    }
  }
}

// ---- vectorized depthwise 4x4 blur: 8 outputs/thread, branch-free ----
struct __align__(8) U4 { unsigned int w[4]; };

__global__ __launch_bounds__(256) void blur2_k(const unsigned short* __restrict__ C,
                                               float* __restrict__ out) {
  const int tid = threadIdx.x;
  const int t  = tid & 31;                  // col block: n in [8t, 8t+8)
  const int m  = blockIdx.x * 8 + (tid >> 5);
  const int oc = blockIdx.y;
  const float cfv[4] = {0.25f, 0.75f, 0.75f, 0.25f};

  float acc[8];
#pragma unroll
  for (int s = 0; s < 8; ++s) acc[s] = 0.f;

#pragma unroll
  for (int i = 0; i < 4; ++i) {
    const int u  = m - 1 + i;
    const int py = u & 1;
    const int r  = (u >> 1) + 1;
    const size_t base = (size_t)r * 136 + 4 * t;
    const U4 ev = *(const U4*)(C + ((size_t)(py * 2 + 0) * OCN + oc) * NROW + base);
    const U4 ov = *(const U4*)(C + ((size_t)(py * 2 + 1) * OCN + oc) * NROW + base);
    float E[8], O[8];
#pragma unroll
    for (int j = 0; j < 4; ++j) {
      E[2 * j]     = __uint_as_float(ev.w[j] << 16);
      E[2 * j + 1] = __uint_as_float(ev.w[j] & 0xffff0000u);
      O[2 * j]     = __uint_as_float(ov.w[j] << 16);
      O[2 * j + 1] = __uint_as_float(ov.w[j] & 0xffff0000u);
    }
    const float cv = cfv[i];
#pragma unroll
    for (int s = 0; s < 8; ++s) {
      float h;
      if ((s & 1) == 0) {
        const int k = s >> 1;
        h = 0.75f * E[k + 1] + 0.25f * E[k + 2] + 0.25f * O[k] + 0.75f * O[k + 1];
      } else {
        const int k = (s + 1) >> 1;
        h = 0.25f * E[k] + 0.75f * E[k + 1] + 0.75f * O[k] + 0.25f * O[k + 1];
      }
      acc[s] += cv * h;
    }
  }

  float* op = out + ((size_t)oc * 256 + m) * 256 + 8 * t;
  f32x4 s0 = {acc[0], acc[1], acc[2], acc[3]};
  f32x4 s1 = {acc[4], acc[5], acc[6], acc[7]};
  *(f32x4*)op = s0;
  *(f32x4*)(op + 4) = s1;
}

extern "C" void kernel_launch(void* const* d_in, const int* in_sizes, int n_in,
                              void* d_out, int out_size, void* d_ws, size_t ws_size,
                              hipStream_t stream) {
  const float* x = (const float*)d_in[0];
  const float* w = (const float*)d_in[1];
  float* out = (float*)d_out;

  // ws layout (bytes):
  //   AP : 9*512*512*2   = 4,718,592    @ 0
  //   XPT: 17936*512*2   = 18,366,464   @ 4,718,592
  //   C  : 4*512*17792*2 = 72,876,032   @ 23,085,056   (total ~96.0 MB)
  __hip_bfloat16* AP  = (__hip_bfloat16*)d_ws;
  __hip_bfloat16* XPT = (__hip_bfloat16*)((char*)d_ws + 4718592);
  __hip_bfloat16* C   = (__hip_bfloat16*)((char*)d_ws + 23085056);

  wprep_k<<<512, 256, 0, stream>>>(w, AP);
  zguard_k<<<256, 256, 0, stream>>>((unsigned int*)XPT);
  packx2_k<<<dim3(130, 8), 256, 0, stream>>>(x, (unsigned int*)XPT);
  gemm_k<<<dim3(70, 2, 4), 512, 0, stream>>>(AP, XPT, C);
  blur2_k<<<dim3(32, 512), 256, 0, stream>>>((const unsigned short*)C, out);
}

// Round 12
// 155.100 us; speedup vs baseline: 1.6032x; 1.0640x over previous
//
#include <hip/hip_runtime.h>
#include <hip/hip_bf16.h>

#define ICN 512
#define OCN 512
#define RS    136      // padded pixel-plane row stride (cols)
#define NROW  17792    // GEMM N cols = 139*128; C plane stride
#define GUARD 144      // zero guard rows in front of XPT (max shift 137)
#define XROWS 17936    // GUARD + NROW

typedef __attribute__((ext_vector_type(8))) short short8;
typedef __attribute__((ext_vector_type(4))) float f32x4;

__device__ __forceinline__ void gload_lds16(const void* g, void* l) {
  __builtin_amdgcn_global_load_lds(
      (const __attribute__((address_space(1))) void*)g,
      (__attribute__((address_space(3))) void*)l, 16, 0, 0);
}

// raw barrier: execution sync WITHOUT vmcnt drain; compiler fences pin LDS ops
__device__ __forceinline__ void bar_raw() {
  asm volatile("" ::: "memory");
  __builtin_amdgcn_s_barrier();
  asm volatile("" ::: "memory");
}

// ---- fused demod + weight pack: AP[tp][oc][ic] = coef[oc]*w[oc][ic][widx(tp)] ----
__global__ __launch_bounds__(256) void wprep_k(const float* __restrict__ w,
                                               __hip_bfloat16* __restrict__ AP) {
  constexpr int WIDX[9] = {0, 2, 6, 8, 1, 7, 3, 5, 4};  // tap -> ky*3+kx
  const int oc = blockIdx.x;
  const int tid = threadIdx.x, lane = tid & 63, wv = tid >> 6;

  float v[2][9];
  float s = 0.f;
#pragma unroll
  for (int rep = 0; rep < 2; ++rep) {
    const int ic = tid + rep * 256;
    const float* wp = w + ((size_t)oc * ICN + ic) * 9;
#pragma unroll
    for (int j = 0; j < 9; ++j) { v[rep][j] = wp[j]; s += wp[j] * wp[j]; }
  }
#pragma unroll
  for (int o = 32; o > 0; o >>= 1) s += __shfl_down(s, o, 64);
  __shared__ float red[4];
  if (lane == 0) red[wv] = s;
  __syncthreads();
  const float tot = red[0] + red[1] + red[2] + red[3];
  const float scale2 = 1.0f / 4608.0f;
  const float c = sqrtf(scale2) * rsqrtf(scale2 * tot + 1e-8f);

#pragma unroll
  for (int rep = 0; rep < 2; ++rep) {
    const int ic = tid + rep * 256;
#pragma unroll
    for (int tp = 0; tp < 9; ++tp)
      AP[((size_t)tp * OCN + oc) * ICN + ic] = __float2bfloat16(c * v[rep][WIDX[tp]]);
  }
}

// ---- x -> bf16 transposed padded pixel space, via LDS transpose tile ----
__global__ __launch_bounds__(256) void packx2_k(const float* __restrict__ x,
                                                unsigned int* __restrict__ XP32) {
  const int py  = blockIdx.x;        // 0..129
  const int ic0 = blockIdx.y * 64;
  const int tid = threadIdx.x;
  const int yy  = py - 1;
  const bool rowvalid = (unsigned)yy < 128u;

  __shared__ __hip_bfloat16 T[128 * 65];   // T[xx][ic_i], padded stride 65

  if (rowvalid) {
    const float4* xr = (const float4*)(x + (size_t)ic0 * 16384 + (size_t)yy * 128);
#pragma unroll
    for (int rep = 0; rep < 8; ++rep) {
      const int idx = rep * 256 + tid;     // 0..2047
      const int x4 = idx & 31, ici = idx >> 5;
      const float4 v = xr[(size_t)ici * 4096 + x4];   // coalesced 16B/lane
      const int xx = x4 * 4;
      T[(xx + 0) * 65 + ici] = __float2bfloat16(v.x);
      T[(xx + 1) * 65 + ici] = __float2bfloat16(v.y);
      T[(xx + 2) * 65 + ici] = __float2bfloat16(v.z);
      T[(xx + 3) * 65 + ici] = __float2bfloat16(v.w);
    }
  }
  __syncthreads();

  const size_t rowbase = (size_t)(GUARD + py * 136) * 256 + (ic0 >> 1);
  for (int rep = 0; rep < 17; ++rep) {
    const int idx = rep * 256 + tid;
    const int px = idx >> 5, j = idx & 31;
    unsigned int uv = 0;
    if (rowvalid && (unsigned)(px - 1) < 128u) {
      union { __hip_bfloat16 h[2]; unsigned int u; } cv;
      cv.h[0] = T[(px - 1) * 65 + 2 * j];
      cv.h[1] = T[(px - 1) * 65 + 2 * j + 1];
      uv = cv.u;
    }
    XP32[rowbase + (size_t)px * 256 + j] = uv;   // coalesced
  }
}

// ---- zero the guard rows [0,144) and tail rows [17824,17936) of XPT ----
__global__ __launch_bounds__(256) void zguard_k(unsigned int* __restrict__ XP32) {
  const int r = blockIdx.x;                       // 0..255
  const int row = (r < 144) ? r : (r + 17680);    // 144->17824 .. 255->17935
  XP32[(size_t)row * 256 + threadIdx.x] = 0;
}

// ---- MFMA implicit GEMM: m201-style 8-phase schedule ----
// BM=BN=256, BK=64 (128B LDS rows), 8 waves (2Mx4N), per-wave 128x64 out.
// 2 LDS buffers (128 KB). Per K-step: 4 phases, each {4 ds_read -> bar ->
// lgkm0 -> setprio1 -> 16 MFMA -> setprio0 -> bar}; stage(t+1) issued in
// phase 0, single vmcnt(0) at phase 3 (loads fly across 6 barriers).
// Swizzle: byte ^= ((row&7)<<4) within 128B rows; linear LDS dest +
// pre-swizzled per-lane global source (involution).
__global__ __launch_bounds__(512, 2) void gemm_k(const __hip_bfloat16* __restrict__ AP,
                                                 const __hip_bfloat16* __restrict__ XPT,
                                                 __hip_bfloat16* __restrict__ C) {
  constexpr int NTt[4]   = {4, 2, 2, 1};
  constexpr int TPO[4]   = {0, 4, 6, 8};
  constexpr int SHIFT[9] = {0, 1, 136, 137, 0, 136, 0, 1, 0};
  constexpr int AR[4]    = {129, 129, 128, 128};
  constexpr int AC[4]    = {129, 128, 129, 128};

  const int n0 = blockIdx.x * 256, oc0 = blockIdx.y * 256, ph = blockIdx.z;
  const int tid = threadIdx.x, lane = tid & 63, wv = tid >> 6;
  const int wr = wv >> 2, wc = wv & 3;            // 2M x 4N wave grid
  const int lane15 = lane & 15, l7 = lane & 7;
  const int kx = (lane >> 4) * 16;                // k-byte offset of lane chunk

  // lds[buf]: A half0 16K | A half1 16K | B half0 16K | B half1 16K
  __shared__ __align__(16) char lds[2 * 65536];

  const int T = NTt[ph] * 8;                      // K-steps of 64

  auto STAGE = [&](int i, char* Lb) {             // tile i -> buffer Lb (8 gloads)
    const int tp = TPO[ph] + (i >> 3);
    const size_t kb = (size_t)(i & 7) * 128;
    const char* Ag = (const char*)AP + (size_t)tp * (512 * 1024) +
                     (size_t)oc0 * 1024 + kb;
    const char* Bg = (const char*)XPT +
                     (size_t)(GUARD + n0 - SHIFT[tp]) * 1024 + kb;
#pragma unroll
    for (int hh = 0; hh < 2; ++hh)
#pragma unroll
      for (int c = 0; c < 2; ++c) {
        const int d = c * 8192 + tid * 16;        // linear byte in 16KB half
        const int r = d >> 7;                     // row 0..127
        const int wk = (d & 127) ^ ((r & 7) << 4);
        gload_lds16(Ag + (size_t)(hh * 128 + r) * 1024 + wk,
                    Lb + hh * 16384 + c * 8192 + wv * 1024);
        gload_lds16(Bg + (size_t)(hh * 128 + r) * 1024 + wk,
                    Lb + 32768 + hh * 16384 + c * 8192 + wv * 1024);
      }
  };

  f32x4 acc[8][4];
#pragma unroll
  for (int m = 0; m < 8; ++m)
#pragma unroll
    for (int n = 0; n < 4; ++n) acc[m][n] = (f32x4){0.f, 0.f, 0.f, 0.f};

  STAGE(0, lds);
  asm volatile("s_waitcnt vmcnt(0)" ::: "memory");
  bar_raw();

  for (int t = 0; t < T; ++t) {
    const int buf = t & 1;
    const char* LA = lds + buf * 65536 + wr * 16384;            // this wave's A half
    const char* LB = lds + buf * 65536 + 32768 + (wc >> 1) * 16384;
    const int brow = (wc & 1) * 64;

    short8 bf[4][2], afA[2][2], afB[2][2];

    // ---- phase 0: B frags + af(m0,m1); issue stage(t+1); MFMA m0,m1 ----
#pragma unroll
    for (int n = 0; n < 4; ++n)
#pragma unroll
      for (int kh = 0; kh < 2; ++kh) {
        const int e = (brow + n * 16 + lane15) * 128 + kh * 64 + kx;
        bf[n][kh] = *(const short8*)(LB + (e ^ (l7 << 4)));
      }
#pragma unroll
    for (int j = 0; j < 2; ++j)
#pragma unroll
      for (int kh = 0; kh < 2; ++kh) {
        const int e = ((0 + j) * 16 + lane15) * 128 + kh * 64 + kx;
        afA[j][kh] = *(const short8*)(LA + (e ^ (l7 << 4)));
      }
    if (t + 1 < T) STAGE(t + 1, lds + (buf ^ 1) * 65536);
    bar_raw();
    asm volatile("s_waitcnt lgkmcnt(0)");
    __builtin_amdgcn_sched_barrier(0);
    __builtin_amdgcn_s_setprio(1);
#pragma unroll
    for (int j = 0; j < 2; ++j)
#pragma unroll
      for (int kh = 0; kh < 2; ++kh)
#pragma unroll
        for (int n = 0; n < 4; ++n)
          acc[0 + j][n] = __builtin_amdgcn_mfma_f32_16x16x32_bf16(afA[j][kh], bf[n][kh], acc[0 + j][n], 0, 0, 0);
    __builtin_amdgcn_s_setprio(0);
    bar_raw();

    // ---- phase 1: af(m2,m3); MFMA m2,m3 ----
#pragma unroll
    for (int j = 0; j < 2; ++j)
#pragma unroll
      for (int kh = 0; kh < 2; ++kh) {
        const int e = ((2 + j) * 16 + lane15) * 128 + kh * 64 + kx;
        afB[j][kh] = *(const short8*)(LA + (e ^ (l7 << 4)));
      }
    bar_raw();
    asm volatile("s_waitcnt lgkmcnt(0)");
    __builtin_amdgcn_sched_barrier(0);
    __builtin_amdgcn_s_setprio(1);
#pragma unroll
    for (int j = 0; j < 2; ++j)
#pragma unroll
      for (int kh = 0; kh < 2; ++kh)
#pragma unroll
        for (int n = 0; n < 4; ++n)
          acc[2 + j][n] = __builtin_amdgcn_mfma_f32_16x16x32_bf16(afB[j][kh], bf[n][kh], acc[2 + j][n], 0, 0, 0);
    __builtin_amdgcn_s_setprio(0);
    bar_raw();

    // ---- phase 2: af(m4,m5); MFMA m4,m5 ----
#pragma unroll
    for (int j = 0; j < 2; ++j)
#pragma unroll
      for (int kh = 0; kh < 2; ++kh) {
        const int e = ((4 + j) * 16 + lane15) * 128 + kh * 64 + kx;
        afA[j][kh] = *(const short8*)(LA + (e ^ (l7 << 4)));
      }
    bar_raw();
    asm volatile("s_waitcnt lgkmcnt(0)");
    __builtin_amdgcn_sched_barrier(0);
    __builtin_amdgcn_s_setprio(1);
#pragma unroll
    for (int j = 0; j < 2; ++j)
#pragma unroll
      for (int kh = 0; kh < 2; ++kh)
#pragma unroll
        for (int n = 0; n < 4; ++n)
          acc[4 + j][n] = __builtin_amdgcn_mfma_f32_16x16x32_bf16(afA[j][kh], bf[n][kh], acc[4 + j][n], 0, 0, 0);
    __builtin_amdgcn_s_setprio(0);
    bar_raw();

    // ---- phase 3: af(m6,m7); MFMA m6,m7; vmcnt(0) once per K-step ----
#pragma unroll
    for (int j = 0; j < 2; ++j)
#pragma unroll
      for (int kh = 0; kh < 2; ++kh) {
        const int e = ((6 + j) * 16 + lane15) * 128 + kh * 64 + kx;
        afB[j][kh] = *(const short8*)(LA + (e ^ (l7 << 4)));
      }
    bar_raw();
    asm volatile("s_waitcnt lgkmcnt(0)");
    __builtin_amdgcn_sched_barrier(0);
    __builtin_amdgcn_s_setprio(1);
#pragma unroll
    for (int j = 0; j < 2; ++j)
#pragma unroll
      for (int kh = 0; kh < 2; ++kh)
#pragma unroll
        for (int n = 0; n < 4; ++n)
          acc[6 + j][n] = __builtin_amdgcn_mfma_f32_16x16x32_bf16(afB[j][kh], bf[n][kh], acc[6 + j][n], 0, 0, 0);
    __builtin_amdgcn_s_setprio(0);
    asm volatile("s_waitcnt vmcnt(0)" ::: "memory");   // tile t+1 landed
    __builtin_amdgcn_sched_barrier(0);
    bar_raw();
  }

  // epilogue: D col = lane&15, row = (lane>>4)*4 + r; mask pad cells to zero
  const int lr = (lane >> 4) * 4, lc = lane & 15;
#pragma unroll
  for (int n = 0; n < 4; ++n) {
    const int col = n0 + wc * 64 + n * 16 + lc;
    if (col < NROW) {
      const int pa = col / 136, pb = col - pa * 136;
      const bool ok = ((unsigned)(pa - 1) < (unsigned)AR[ph]) &&
                      ((unsigned)(pb - 1) < (unsigned)AC[ph]);
#pragma unroll
      for (int m = 0; m < 8; ++m)
#pragma unroll
        for (int r = 0; r < 4; ++r) {
          const int row = oc0 + wr * 128 + m * 16 + lr + r;
          C[((size_t)(ph * OCN + row)) * NROW + col] =
              __float2bfloat16(ok ? acc[m][n][r] : 0.f);
        }
    }
  }
}

// ---- vectorized depthwise 4x4 blur: 8 outputs/thread, branch-free ----
struct __align__(8) U4 { unsigned int w[4]; };

__global__ __launch_bounds__(256) void blur2_k(const unsigned short* __restrict__ C,
                                               float* __restrict__ out) {
  const int tid = threadIdx.x;
  const int t  = tid & 31;                  // col block: n in [8t, 8t+8)
  const int m  = blockIdx.x * 8 + (tid >> 5);
  const int oc = blockIdx.y;
  const float cfv[4] = {0.25f, 0.75f, 0.75f, 0.25f};

  float acc[8];
#pragma unroll
  for (int s = 0; s < 8; ++s) acc[s] = 0.f;

#pragma unroll
  for (int i = 0; i < 4; ++i) {
    const int u  = m - 1 + i;
    const int py = u & 1;
    const int r  = (u >> 1) + 1;
    const size_t base = (size_t)r * 136 + 4 * t;
    const U4 ev = *(const U4*)(C + ((size_t)(py * 2 + 0) * OCN + oc) * NROW + base);
    const U4 ov = *(const U4*)(C + ((size_t)(py * 2 + 1) * OCN + oc) * NROW + base);
    float E[8], O[8];
#pragma unroll
    for (int j = 0; j < 4; ++j) {
      E[2 * j]     = __uint_as_float(ev.w[j] << 16);
      E[2 * j + 1] = __uint_as_float(ev.w[j] & 0xffff0000u);
      O[2 * j]     = __uint_as_float(ov.w[j] << 16);
      O[2 * j + 1] = __uint_as_float(ov.w[j] & 0xffff0000u);
    }
    const float cv = cfv[i];
#pragma unroll
    for (int s = 0; s < 8; ++s) {
      float h;
      if ((s & 1) == 0) {
        const int k = s >> 1;
        h = 0.75f * E[k + 1] + 0.25f * E[k + 2] + 0.25f * O[k] + 0.75f * O[k + 1];
      } else {
        const int k = (s + 1) >> 1;
        h = 0.25f * E[k] + 0.75f * E[k + 1] + 0.75f * O[k] + 0.25f * O[k + 1];
      }
      acc[s] += cv * h;
    }
  }

  float* op = out + ((size_t)oc * 256 + m) * 256 + 8 * t;
  f32x4 s0 = {acc[0], acc[1], acc[2], acc[3]};
  f32x4 s1 = {acc[4], acc[5], acc[6], acc[7]};
  *(f32x4*)op = s0;
  *(f32x4*)(op + 4) = s1;
}

extern "C" void kernel_launch(void* const* d_in, const int* in_sizes, int n_in,
                              void* d_out, int out_size, void* d_ws, size_t ws_size,
                              hipStream_t stream) {
  const float* x = (const float*)d_in[0];
  const float* w = (const float*)d_in[1];
  float* out = (float*)d_out;

  // ws layout (bytes):
  //   AP : 9*512*512*2   = 4,718,592    @ 0
  //   XPT: 17936*512*2   = 18,366,464   @ 4,718,592
  //   C  : 4*512*17792*2 = 72,876,032   @ 23,085,056   (total ~96.0 MB)
  __hip_bfloat16* AP  = (__hip_bfloat16*)d_ws;
  __hip_bfloat16* XPT = (__hip_bfloat16*)((char*)d_ws + 4718592);
  __hip_bfloat16* C   = (__hip_bfloat16*)((char*)d_ws + 23085056);

  wprep_k<<<512, 256, 0, stream>>>(w, AP);
  zguard_k<<<256, 256, 0, stream>>>((unsigned int*)XPT);
  packx2_k<<<dim3(130, 8), 256, 0, stream>>>(x, (unsigned int*)XPT);
  gemm_k<<<dim3(70, 2, 4), 512, 0, stream>>>(AP, XPT, C);
  blur2_k<<<dim3(32, 512), 256, 0, stream>>>((const unsigned short*)C, out);
}

// Round 13
// 145.965 us; speedup vs baseline: 1.7035x; 1.0626x over previous
//
#include <hip/hip_runtime.h>
#include <hip/hip_bf16.h>

#define ICN 512
#define OCN 512
#define RS    136      // padded pixel-plane row stride (cols)
#define NROW  17792    // GEMM N cols = 139*128; C plane stride
#define GUARD 144      // zero guard rows in front of XPT (max shift 137)
#define XROWS 17936    // GUARD + NROW

typedef __attribute__((ext_vector_type(8))) short short8;
typedef __attribute__((ext_vector_type(4))) float f32x4;

__device__ __forceinline__ void gload_lds16(const void* g, void* l) {
  __builtin_amdgcn_global_load_lds(
      (const __attribute__((address_space(1))) void*)g,
      (__attribute__((address_space(3))) void*)l, 16, 0, 0);
}

// raw barrier: execution sync WITHOUT vmcnt drain; compiler fences pin LDS ops
__device__ __forceinline__ void bar_raw() {
  asm volatile("" ::: "memory");
  __builtin_amdgcn_s_barrier();
  asm volatile("" ::: "memory");
}

// ---- fused demod + weight pack: AP[tp][oc][ic] = coef[oc]*w[oc][ic][widx(tp)] ----
__global__ __launch_bounds__(256) void wprep_k(const float* __restrict__ w,
                                               __hip_bfloat16* __restrict__ AP) {
  constexpr int WIDX[9] = {0, 2, 6, 8, 1, 7, 3, 5, 4};  // tap -> ky*3+kx
  const int oc = blockIdx.x;
  const int tid = threadIdx.x, lane = tid & 63, wv = tid >> 6;

  float v[2][9];
  float s = 0.f;
#pragma unroll
  for (int rep = 0; rep < 2; ++rep) {
    const int ic = tid + rep * 256;
    const float* wp = w + ((size_t)oc * ICN + ic) * 9;
#pragma unroll
    for (int j = 0; j < 9; ++j) { v[rep][j] = wp[j]; s += wp[j] * wp[j]; }
  }
#pragma unroll
  for (int o = 32; o > 0; o >>= 1) s += __shfl_down(s, o, 64);
  __shared__ float red[4];
  if (lane == 0) red[wv] = s;
  __syncthreads();
  const float tot = red[0] + red[1] + red[2] + red[3];
  const float scale2 = 1.0f / 4608.0f;
  const float c = sqrtf(scale2) * rsqrtf(scale2 * tot + 1e-8f);

#pragma unroll
  for (int rep = 0; rep < 2; ++rep) {
    const int ic = tid + rep * 256;
#pragma unroll
    for (int tp = 0; tp < 9; ++tp)
      AP[((size_t)tp * OCN + oc) * ICN + ic] = __float2bfloat16(c * v[rep][WIDX[tp]]);
  }
}

// ---- x -> bf16 transposed padded pixel space, via LDS transpose tile ----
__global__ __launch_bounds__(256) void packx2_k(const float* __restrict__ x,
                                                unsigned int* __restrict__ XP32) {
  const int py  = blockIdx.x;        // 0..129
  const int ic0 = blockIdx.y * 64;
  const int tid = threadIdx.x;
  const int yy  = py - 1;
  const bool rowvalid = (unsigned)yy < 128u;

  __shared__ __hip_bfloat16 T[128 * 65];   // T[xx][ic_i], padded stride 65

  if (rowvalid) {
    const float4* xr = (const float4*)(x + (size_t)ic0 * 16384 + (size_t)yy * 128);
#pragma unroll
    for (int rep = 0; rep < 8; ++rep) {
      const int idx = rep * 256 + tid;     // 0..2047
      const int x4 = idx & 31, ici = idx >> 5;
      const float4 v = xr[(size_t)ici * 4096 + x4];   // coalesced 16B/lane
      const int xx = x4 * 4;
      T[(xx + 0) * 65 + ici] = __float2bfloat16(v.x);
      T[(xx + 1) * 65 + ici] = __float2bfloat16(v.y);
      T[(xx + 2) * 65 + ici] = __float2bfloat16(v.z);
      T[(xx + 3) * 65 + ici] = __float2bfloat16(v.w);
    }
  }
  __syncthreads();

  const size_t rowbase = (size_t)(GUARD + py * 136) * 256 + (ic0 >> 1);
  for (int rep = 0; rep < 17; ++rep) {
    const int idx = rep * 256 + tid;
    const int px = idx >> 5, j = idx & 31;
    unsigned int uv = 0;
    if (rowvalid && (unsigned)(px - 1) < 128u) {
      union { __hip_bfloat16 h[2]; unsigned int u; } cv;
      cv.h[0] = T[(px - 1) * 65 + 2 * j];
      cv.h[1] = T[(px - 1) * 65 + 2 * j + 1];
      uv = cv.u;
    }
    XP32[rowbase + (size_t)px * 256 + j] = uv;   // coalesced
  }
}

// ---- zero the guard rows [0,144) and tail rows [17824,17936) of XPT ----
__global__ __launch_bounds__(256) void zguard_k(unsigned int* __restrict__ XP32) {
  const int r = blockIdx.x;                       // 0..255
  const int row = (r < 144) ? r : (r + 17680);    // 144->17824 .. 255->17935
  XP32[(size_t)row * 256 + threadIdx.x] = 0;
}

// ---- MFMA implicit GEMM: counted-lgkmcnt pipeline, 1 barrier per K-step ----
// BM=BN=256, BK=64 (128B LDS rows), 8 waves (2Mx4N), per-wave 128x64 out.
// 2 LDS buffers (128 KB). Per K-step: issue reads group g+1 BEFORE MFMA
// group g; counted lgkmcnt(4) (DS completes in order); single s_barrier per
// K-step with vmcnt(0)+lgkmcnt(0) just before it. Stage loads fly under the
// whole K-step's MFMA. Swizzle byte^=((row&7)<<4); linear LDS dest +
// pre-swizzled per-lane global source (involution).
__global__ __launch_bounds__(512, 2) void gemm_k(const __hip_bfloat16* __restrict__ AP,
                                                 const __hip_bfloat16* __restrict__ XPT,
                                                 __hip_bfloat16* __restrict__ C) {
  constexpr int NTt[4]   = {4, 2, 2, 1};
  constexpr int TPO[4]   = {0, 4, 6, 8};
  constexpr int SHIFT[9] = {0, 1, 136, 137, 0, 136, 0, 1, 0};
  constexpr int AR[4]    = {129, 129, 128, 128};
  constexpr int AC[4]    = {129, 128, 129, 128};

  const int n0 = blockIdx.x * 256, oc0 = blockIdx.y * 256, ph = blockIdx.z;
  const int tid = threadIdx.x, lane = tid & 63, wv = tid >> 6;
  const int wr = wv >> 2, wc = wv & 3;            // 2M x 4N wave grid
  const int lane15 = lane & 15, l7 = lane & 7;
  const int kx = (lane >> 4) * 16;                // k-byte offset of lane chunk

  // lds[buf]: A half0 16K | A half1 16K | B half0 16K | B half1 16K
  __shared__ __align__(16) char lds[2 * 65536];

  const int T = NTt[ph] * 8;                      // K-steps of 64

  auto STAGE = [&](int i, char* Lb) {             // tile i -> buffer Lb (8 gloads)
    const int tp = TPO[ph] + (i >> 3);
    const size_t kb = (size_t)(i & 7) * 128;
    const char* Ag = (const char*)AP + (size_t)tp * (512 * 1024) +
                     (size_t)oc0 * 1024 + kb;
    const char* Bg = (const char*)XPT +
                     (size_t)(GUARD + n0 - SHIFT[tp]) * 1024 + kb;
#pragma unroll
    for (int hh = 0; hh < 2; ++hh)
#pragma unroll
      for (int c = 0; c < 2; ++c) {
        const int d = c * 8192 + tid * 16;        // linear byte in 16KB half
        const int r = d >> 7;                     // row 0..127
        const int wk = (d & 127) ^ ((r & 7) << 4);
        gload_lds16(Ag + (size_t)(hh * 128 + r) * 1024 + wk,
                    Lb + hh * 16384 + c * 8192 + wv * 1024);
        gload_lds16(Bg + (size_t)(hh * 128 + r) * 1024 + wk,
                    Lb + 32768 + hh * 16384 + c * 8192 + wv * 1024);
      }
  };

  f32x4 acc[8][4];
#pragma unroll
  for (int m = 0; m < 8; ++m)
#pragma unroll
    for (int n = 0; n < 4; ++n) acc[m][n] = (f32x4){0.f, 0.f, 0.f, 0.f};

  STAGE(0, lds);
  asm volatile("s_waitcnt vmcnt(0)" ::: "memory");
  bar_raw();

  for (int t = 0; t < T; ++t) {
    const int buf = t & 1;
    const char* LA = lds + buf * 65536 + wr * 16384;            // wave's A half
    const char* LB = lds + buf * 65536 + 32768 + (wc >> 1) * 16384;
    const int brow = (wc & 1) * 64;

    short8 bf[4][2], af0[2][2], af1[2][2];

    // issue: bf (8 reads) + af m0,m1 (4 reads); then stage(t+1); then af m2,m3
#pragma unroll
    for (int n = 0; n < 4; ++n)
#pragma unroll
      for (int kh = 0; kh < 2; ++kh) {
        const int e = (brow + n * 16 + lane15) * 128 + kh * 64 + kx;
        bf[n][kh] = *(const short8*)(LB + (e ^ (l7 << 4)));
      }
#pragma unroll
    for (int j = 0; j < 2; ++j)
#pragma unroll
      for (int kh = 0; kh < 2; ++kh) {
        const int e = ((0 + j) * 16 + lane15) * 128 + kh * 64 + kx;
        af0[j][kh] = *(const short8*)(LA + (e ^ (l7 << 4)));
      }
    __builtin_amdgcn_sched_barrier(0);
    {
      const int ts = (t + 1 < T) ? (t + 1) : (T - 1);   // tail: dummy re-stage
      STAGE(ts, lds + (buf ^ 1) * 65536);
    }
    __builtin_amdgcn_sched_barrier(0);
#pragma unroll
    for (int j = 0; j < 2; ++j)
#pragma unroll
      for (int kh = 0; kh < 2; ++kh) {
        const int e = ((2 + j) * 16 + lane15) * 128 + kh * 64 + kx;
        af1[j][kh] = *(const short8*)(LA + (e ^ (l7 << 4)));
      }
    __builtin_amdgcn_sched_barrier(0);

    // group 0: wait bf+af01 (af23 outstanding), MFMA m0,m1
    asm volatile("s_waitcnt lgkmcnt(4)");
    __builtin_amdgcn_sched_barrier(0);
    __builtin_amdgcn_s_setprio(1);
#pragma unroll
    for (int j = 0; j < 2; ++j)
#pragma unroll
      for (int kh = 0; kh < 2; ++kh)
#pragma unroll
        for (int n = 0; n < 4; ++n)
          acc[0 + j][n] = __builtin_amdgcn_mfma_f32_16x16x32_bf16(af0[j][kh], bf[n][kh], acc[0 + j][n], 0, 0, 0);
    __builtin_amdgcn_s_setprio(0);
    __builtin_amdgcn_sched_barrier(0);

    // issue af m4,m5 (into af0); wait af23; MFMA m2,m3
#pragma unroll
    for (int j = 0; j < 2; ++j)
#pragma unroll
      for (int kh = 0; kh < 2; ++kh) {
        const int e = ((4 + j) * 16 + lane15) * 128 + kh * 64 + kx;
        af0[j][kh] = *(const short8*)(LA + (e ^ (l7 << 4)));
      }
    __builtin_amdgcn_sched_barrier(0);
    asm volatile("s_waitcnt lgkmcnt(4)");
    __builtin_amdgcn_sched_barrier(0);
    __builtin_amdgcn_s_setprio(1);
#pragma unroll
    for (int j = 0; j < 2; ++j)
#pragma unroll
      for (int kh = 0; kh < 2; ++kh)
#pragma unroll
        for (int n = 0; n < 4; ++n)
          acc[2 + j][n] = __builtin_amdgcn_mfma_f32_16x16x32_bf16(af1[j][kh], bf[n][kh], acc[2 + j][n], 0, 0, 0);
    __builtin_amdgcn_s_setprio(0);
    __builtin_amdgcn_sched_barrier(0);

    // issue af m6,m7 (into af1); wait af45; MFMA m4,m5
#pragma unroll
    for (int j = 0; j < 2; ++j)
#pragma unroll
      for (int kh = 0; kh < 2; ++kh) {
        const int e = ((6 + j) * 16 + lane15) * 128 + kh * 64 + kx;
        af1[j][kh] = *(const short8*)(LA + (e ^ (l7 << 4)));
      }
    __builtin_amdgcn_sched_barrier(0);
    asm volatile("s_waitcnt lgkmcnt(4)");
    __builtin_amdgcn_sched_barrier(0);
    __builtin_amdgcn_s_setprio(1);
#pragma unroll
    for (int j = 0; j < 2; ++j)
#pragma unroll
      for (int kh = 0; kh < 2; ++kh)
#pragma unroll
        for (int n = 0; n < 4; ++n)
          acc[4 + j][n] = __builtin_amdgcn_mfma_f32_16x16x32_bf16(af0[j][kh], bf[n][kh], acc[4 + j][n], 0, 0, 0);
    __builtin_amdgcn_s_setprio(0);
    __builtin_amdgcn_sched_barrier(0);

    // wait af67; MFMA m6,m7
    asm volatile("s_waitcnt lgkmcnt(0)");
    __builtin_amdgcn_sched_barrier(0);
    __builtin_amdgcn_s_setprio(1);
#pragma unroll
    for (int j = 0; j < 2; ++j)
#pragma unroll
      for (int kh = 0; kh < 2; ++kh)
#pragma unroll
        for (int n = 0; n < 4; ++n)
          acc[6 + j][n] = __builtin_amdgcn_mfma_f32_16x16x32_bf16(af1[j][kh], bf[n][kh], acc[6 + j][n], 0, 0, 0);
    __builtin_amdgcn_s_setprio(0);

    // single cross-wave handshake per K-step:
    // my reads of buf done (lgkm 0 above) + my stage of buf^1 landed
    asm volatile("s_waitcnt vmcnt(0)" ::: "memory");
    __builtin_amdgcn_sched_barrier(0);
    bar_raw();
  }

  // epilogue: D col = lane&15, row = (lane>>4)*4 + r; mask pad cells to zero
  const int lr = (lane >> 4) * 4, lc = lane & 15;
#pragma unroll
  for (int n = 0; n < 4; ++n) {
    const int col = n0 + wc * 64 + n * 16 + lc;
    if (col < NROW) {
      const int pa = col / 136, pb = col - pa * 136;
      const bool ok = ((unsigned)(pa - 1) < (unsigned)AR[ph]) &&
                      ((unsigned)(pb - 1) < (unsigned)AC[ph]);
#pragma unroll
      for (int m = 0; m < 8; ++m)
#pragma unroll
        for (int r = 0; r < 4; ++r) {
          const int row = oc0 + wr * 128 + m * 16 + lr + r;
          C[((size_t)(ph * OCN + row)) * NROW + col] =
              __float2bfloat16(ok ? acc[m][n][r] : 0.f);
        }
    }
  }
}

// ---- vectorized depthwise 4x4 blur: 8 outputs/thread, branch-free ----
struct __align__(8) U4 { unsigned int w[4]; };

__global__ __launch_bounds__(256) void blur2_k(const unsigned short* __restrict__ C,
                                               float* __restrict__ out) {
  const int tid = threadIdx.x;
  const int t  = tid & 31;                  // col block: n in [8t, 8t+8)
  const int m  = blockIdx.x * 8 + (tid >> 5);
  const int oc = blockIdx.y;
  const float cfv[4] = {0.25f, 0.75f, 0.75f, 0.25f};

  float acc[8];
#pragma unroll
  for (int s = 0; s < 8; ++s) acc[s] = 0.f;

#pragma unroll
  for (int i = 0; i < 4; ++i) {
    const int u  = m - 1 + i;
    const int py = u & 1;
    const int r  = (u >> 1) + 1;
    const size_t base = (size_t)r * 136 + 4 * t;
    const U4 ev = *(const U4*)(C + ((size_t)(py * 2 + 0) * OCN + oc) * NROW + base);
    const U4 ov = *(const U4*)(C + ((size_t)(py * 2 + 1) * OCN + oc) * NROW + base);
    float E[8], O[8];
#pragma unroll
    for (int j = 0; j < 4; ++j) {
      E[2 * j]     = __uint_as_float(ev.w[j] << 16);
      E[2 * j + 1] = __uint_as_float(ev.w[j] & 0xffff0000u);
      O[2 * j]     = __uint_as_float(ov.w[j] << 16);
      O[2 * j + 1] = __uint_as_float(ov.w[j] & 0xffff0000u);
    }
    const float cv = cfv[i];
#pragma unroll
    for (int s = 0; s < 8; ++s) {
      float h;
      if ((s & 1) == 0) {
        const int k = s >> 1;
        h = 0.75f * E[k + 1] + 0.25f * E[k + 2] + 0.25f * O[k] + 0.75f * O[k + 1];
      } else {
        const int k = (s + 1) >> 1;
        h = 0.25f * E[k] + 0.75f * E[k + 1] + 0.75f * O[k] + 0.25f * O[k + 1];
      }
      acc[s] += cv * h;
    }
  }

  float* op = out + ((size_t)oc * 256 + m) * 256 + 8 * t;
  f32x4 s0 = {acc[0], acc[1], acc[2], acc[3]};
  f32x4 s1 = {acc[4], acc[5], acc[6], acc[7]};
  *(f32x4*)op = s0;
  *(f32x4*)(op + 4) = s1;
}

extern "C" void kernel_launch(void* const* d_in, const int* in_sizes, int n_in,
                              void* d_out, int out_size, void* d_ws, size_t ws_size,
                              hipStream_t stream) {
  const float* x = (const float*)d_in[0];
  const float* w = (const float*)d_in[1];
  float* out = (float*)d_out;

  // ws layout (bytes):
  //   AP : 9*512*512*2   = 4,718,592    @ 0
  //   XPT: 17936*512*2   = 18,366,464   @ 4,718,592
  //   C  : 4*512*17792*2 = 72,876,032   @ 23,085,056   (total ~96.0 MB)
  __hip_bfloat16* AP  = (__hip_bfloat16*)d_ws;
  __hip_bfloat16* XPT = (__hip_bfloat16*)((char*)d_ws + 4718592);
  __hip_bfloat16* C   = (__hip_bfloat16*)((char*)d_ws + 23085056);

  wprep_k<<<512, 256, 0, stream>>>(w, AP);
  zguard_k<<<256, 256, 0, stream>>>((unsigned int*)XPT);
  packx2_k<<<dim3(130, 8), 256, 0, stream>>>(x, (unsigned int*)XPT);
  gemm_k<<<dim3(70, 2, 4), 512, 0, stream>>>(AP, XPT, C);
  blur2_k<<<dim3(32, 512), 256, 0, stream>>>((const unsigned short*)C, out);
}

// Round 14
// 145.294 us; speedup vs baseline: 1.7114x; 1.0046x over previous
//
#include <hip/hip_runtime.h>
#include <hip/hip_bf16.h>

#define ICN 512
#define OCN 512
#define RS    136      // padded pixel-plane row stride (cols)
#define NROW  17792    // GEMM N cols = 139*128; C plane stride
#define GUARD 144      // zero guard rows in front of XPT (max shift 137)
#define XROWS 17936    // GUARD + NROW

typedef __attribute__((ext_vector_type(8))) short short8;
typedef __attribute__((ext_vector_type(4))) float f32x4;

__device__ __forceinline__ void gload_lds16(const void* g, void* l) {
  __builtin_amdgcn_global_load_lds(
      (const __attribute__((address_space(1))) void*)g,
      (__attribute__((address_space(3))) void*)l, 16, 0, 0);
}

// raw barrier: execution sync WITHOUT vmcnt drain; compiler fences pin LDS ops
__device__ __forceinline__ void bar_raw() {
  asm volatile("" ::: "memory");
  __builtin_amdgcn_s_barrier();
  asm volatile("" ::: "memory");
}

#define SB0() __builtin_amdgcn_sched_barrier(0)

// ---- fused demod + weight pack: AP[tp][oc][ic] = coef[oc]*w[oc][ic][widx(tp)] ----
__global__ __launch_bounds__(256) void wprep_k(const float* __restrict__ w,
                                               __hip_bfloat16* __restrict__ AP) {
  constexpr int WIDX[9] = {0, 2, 6, 8, 1, 7, 3, 5, 4};  // tap -> ky*3+kx
  const int oc = blockIdx.x;
  const int tid = threadIdx.x, lane = tid & 63, wv = tid >> 6;

  float v[2][9];
  float s = 0.f;
#pragma unroll
  for (int rep = 0; rep < 2; ++rep) {
    const int ic = tid + rep * 256;
    const float* wp = w + ((size_t)oc * ICN + ic) * 9;
#pragma unroll
    for (int j = 0; j < 9; ++j) { v[rep][j] = wp[j]; s += wp[j] * wp[j]; }
  }
#pragma unroll
  for (int o = 32; o > 0; o >>= 1) s += __shfl_down(s, o, 64);
  __shared__ float red[4];
  if (lane == 0) red[wv] = s;
  __syncthreads();
  const float tot = red[0] + red[1] + red[2] + red[3];
  const float scale2 = 1.0f / 4608.0f;
  const float c = sqrtf(scale2) * rsqrtf(scale2 * tot + 1e-8f);

#pragma unroll
  for (int rep = 0; rep < 2; ++rep) {
    const int ic = tid + rep * 256;
#pragma unroll
    for (int tp = 0; tp < 9; ++tp)
      AP[((size_t)tp * OCN + oc) * ICN + ic] = __float2bfloat16(c * v[rep][WIDX[tp]]);
  }
}

// ---- x -> bf16 transposed padded pixel space, via LDS transpose tile ----
__global__ __launch_bounds__(256) void packx2_k(const float* __restrict__ x,
                                                unsigned int* __restrict__ XP32) {
  const int py  = blockIdx.x;        // 0..129
  const int ic0 = blockIdx.y * 64;
  const int tid = threadIdx.x;
  const int yy  = py - 1;
  const bool rowvalid = (unsigned)yy < 128u;

  __shared__ __hip_bfloat16 T[128 * 65];   // T[xx][ic_i], padded stride 65

  if (rowvalid) {
    const float4* xr = (const float4*)(x + (size_t)ic0 * 16384 + (size_t)yy * 128);
#pragma unroll
    for (int rep = 0; rep < 8; ++rep) {
      const int idx = rep * 256 + tid;     // 0..2047
      const int x4 = idx & 31, ici = idx >> 5;
      const float4 v = xr[(size_t)ici * 4096 + x4];   // coalesced 16B/lane
      const int xx = x4 * 4;
      T[(xx + 0) * 65 + ici] = __float2bfloat16(v.x);
      T[(xx + 1) * 65 + ici] = __float2bfloat16(v.y);
      T[(xx + 2) * 65 + ici] = __float2bfloat16(v.z);
      T[(xx + 3) * 65 + ici] = __float2bfloat16(v.w);
    }
  }
  __syncthreads();

  const size_t rowbase = (size_t)(GUARD + py * 136) * 256 + (ic0 >> 1);
  for (int rep = 0; rep < 17; ++rep) {
    const int idx = rep * 256 + tid;
    const int px = idx >> 5, j = idx & 31;
    unsigned int uv = 0;
    if (rowvalid && (unsigned)(px - 1) < 128u) {
      union { __hip_bfloat16 h[2]; unsigned int u; } cv;
      cv.h[0] = T[(px - 1) * 65 + 2 * j];
      cv.h[1] = T[(px - 1) * 65 + 2 * j + 1];
      uv = cv.u;
    }
    XP32[rowbase + (size_t)px * 256 + j] = uv;   // coalesced
  }
}

// ---- zero the guard rows [0,144) and tail rows [17824,17936) of XPT ----
__global__ __launch_bounds__(256) void zguard_k(unsigned int* __restrict__ XP32) {
  const int r = blockIdx.x;                       // 0..255
  const int row = (r < 144) ? r : (r + 17680);    // 144->17824 .. 255->17935
  XP32[(size_t)row * 256 + threadIdx.x] = 0;
}

// ---- MFMA implicit GEMM: fine 8-cluster interleave, 1 barrier per K-step ----
// BM=BN=256, BK=64 (128B LDS rows), 8 waves (2Mx4N), per-wave 128x64 out.
// Per K-step: 8 clusters of {<=2 ds_read issue -> lgkmcnt(2) lookahead ->
// 8 MFMA}, grouped by (m-pair, kh); STAGE gloads spread in pairs after
// clusters c0..c3; single vmcnt(0)+s_barrier per K-step. Swizzle
// byte^=((row&7)<<4); linear LDS dest + pre-swizzled global source.
__global__ __launch_bounds__(512, 2) void gemm_k(const __hip_bfloat16* __restrict__ AP,
                                                 const __hip_bfloat16* __restrict__ XPT,
                                                 __hip_bfloat16* __restrict__ C) {
  constexpr int NTt[4]   = {4, 2, 2, 1};
  constexpr int TPO[4]   = {0, 4, 6, 8};
  constexpr int SHIFT[9] = {0, 1, 136, 137, 0, 136, 0, 1, 0};
  constexpr int AR[4]    = {129, 129, 128, 128};
  constexpr int AC[4]    = {129, 128, 129, 128};

  const int n0 = blockIdx.x * 256, oc0 = blockIdx.y * 256, ph = blockIdx.z;
  const int tid = threadIdx.x, lane = tid & 63, wv = tid >> 6;
  const int wr = wv >> 2, wc = wv & 3;            // 2M x 4N wave grid
  const int lane15 = lane & 15, l7 = lane & 7;
  const int kx = (lane >> 4) * 16;                // k-byte offset of lane chunk

  // lds[buf]: A half0 16K | A half1 16K | B half0 16K | B half1 16K
  __shared__ __align__(16) char lds[2 * 65536];

  const int T = NTt[ph] * 8;                      // K-steps of 64

  // staging geometry (uniform per thread across steps)
  const int r0  = tid >> 3;                       // base row 0..63
  const int wk0 = ((tid * 16) & 127) ^ ((r0 & 7) << 4);

  auto STG = [&](const char* Ag, const char* Bg, char* Lnext, int g) {
    const int hh = (g >> 1) & 1, c = g & 1;
    if (g < 4)
      gload_lds16(Ag + (size_t)(hh * 128 + r0 + c * 64) * 1024 + wk0,
                  Lnext + hh * 16384 + c * 8192 + wv * 1024);
    else
      gload_lds16(Bg + (size_t)(hh * 128 + r0 + c * 64) * 1024 + wk0,
                  Lnext + 32768 + hh * 16384 + c * 8192 + wv * 1024);
  };

  f32x4 acc[8][4];
#pragma unroll
  for (int m = 0; m < 8; ++m)
#pragma unroll
    for (int n = 0; n < 4; ++n) acc[m][n] = (f32x4){0.f, 0.f, 0.f, 0.f};

  // prologue: full stage of tile 0
  {
    const int tp = TPO[ph];
    const char* Ag = (const char*)AP + (size_t)tp * (512 * 1024) + (size_t)oc0 * 1024;
    const char* Bg = (const char*)XPT + (size_t)(GUARD + n0 - SHIFT[tp]) * 1024;
#pragma unroll
    for (int g = 0; g < 8; ++g) STG(Ag, Bg, lds, g);
  }
  asm volatile("s_waitcnt vmcnt(0)" ::: "memory");
  bar_raw();

#define DSR(dst, base, row, khh)                                            \
  { const int e_ = (row) * 128 + (khh) * 64 + kx;                           \
    dst = *(const short8*)((base) + (e_ ^ (l7 << 4))); }

#define MFMA8(mb, afv, bfv)                                                 \
  _Pragma("unroll") for (int j = 0; j < 2; ++j)                             \
  _Pragma("unroll") for (int n = 0; n < 4; ++n)                             \
    acc[(mb) + j][n] = __builtin_amdgcn_mfma_f32_16x16x32_bf16(             \
        afv[j], bfv[n], acc[(mb) + j][n], 0, 0, 0);

  for (int t = 0; t < T; ++t) {
    const int buf = t & 1;
    const char* LA = lds + buf * 65536 + wr * 16384;            // wave's A half
    const char* LB = lds + buf * 65536 + 32768 + (wc >> 1) * 16384;
    const int brow = (wc & 1) * 64;
    char* Lnext = lds + (buf ^ 1) * 65536;
    const int ts = (t + 1 < T) ? (t + 1) : (T - 1);             // tail: dummy
    const int tp = TPO[ph] + (ts >> 3);
    const size_t kb = (size_t)(ts & 7) * 128;
    const char* Ag = (const char*)AP + (size_t)tp * (512 * 1024) +
                     (size_t)oc0 * 1024 + kb;
    const char* Bg = (const char*)XPT +
                     (size_t)(GUARD + n0 - SHIFT[tp]) * 1024 + kb;

    short8 bf0[4], bf1[4], afA[2], afB[2];

    // I0: bf(kh0) x4 + af(m01,kh0) x2
#pragma unroll
    for (int n = 0; n < 4; ++n) DSR(bf0[n], LB, brow + n * 16 + lane15, 0);
    DSR(afA[0], LA, 0 * 16 + lane15, 0);
    DSR(afA[1], LA, 1 * 16 + lane15, 0);
    SB0();
    // I1: bf(kh1) x4 + af(m01,kh1) x2
#pragma unroll
    for (int n = 0; n < 4; ++n) DSR(bf1[n], LB, brow + n * 16 + lane15, 1);
    DSR(afB[0], LA, 0 * 16 + lane15, 1);
    DSR(afB[1], LA, 1 * 16 + lane15, 1);
    SB0();
    asm volatile("s_waitcnt lgkmcnt(6)");   // I0 ready
    SB0();
    __builtin_amdgcn_s_setprio(1); MFMA8(0, afA, bf0); __builtin_amdgcn_s_setprio(0);
    SB0(); STG(Ag, Bg, Lnext, 0); STG(Ag, Bg, Lnext, 1); SB0();

    DSR(afA[0], LA, 2 * 16 + lane15, 0);    // I2: af(m23,kh0)
    DSR(afA[1], LA, 3 * 16 + lane15, 0);
    SB0();
    asm volatile("s_waitcnt lgkmcnt(2)");   // I1 ready
    SB0();
    __builtin_amdgcn_s_setprio(1); MFMA8(0, afB, bf1); __builtin_amdgcn_s_setprio(0);
    SB0(); STG(Ag, Bg, Lnext, 2); STG(Ag, Bg, Lnext, 3); SB0();

    DSR(afB[0], LA, 2 * 16 + lane15, 1);    // I3: af(m23,kh1)
    DSR(afB[1], LA, 3 * 16 + lane15, 1);
    SB0();
    asm volatile("s_waitcnt lgkmcnt(2)");   // I2 ready
    SB0();
    __builtin_amdgcn_s_setprio(1); MFMA8(2, afA, bf0); __builtin_amdgcn_s_setprio(0);
    SB0(); STG(Ag, Bg, Lnext, 4); STG(Ag, Bg, Lnext, 5); SB0();

    DSR(afA[0], LA, 4 * 16 + lane15, 0);    // I4: af(m45,kh0)
    DSR(afA[1], LA, 5 * 16 + lane15, 0);
    SB0();
    asm volatile("s_waitcnt lgkmcnt(2)");   // I3 ready
    SB0();
    __builtin_amdgcn_s_setprio(1); MFMA8(2, afB, bf1); __builtin_amdgcn_s_setprio(0);
    SB0(); STG(Ag, Bg, Lnext, 6); STG(Ag, Bg, Lnext, 7); SB0();

    DSR(afB[0], LA, 4 * 16 + lane15, 1);    // I5: af(m45,kh1)
    DSR(afB[1], LA, 5 * 16 + lane15, 1);
    SB0();
    asm volatile("s_waitcnt lgkmcnt(2)");   // I4 ready
    SB0();
    __builtin_amdgcn_s_setprio(1); MFMA8(4, afA, bf0); __builtin_amdgcn_s_setprio(0);
    SB0();

    DSR(afA[0], LA, 6 * 16 + lane15, 0);    // I6: af(m67,kh0)
    DSR(afA[1], LA, 7 * 16 + lane15, 0);
    SB0();
    asm volatile("s_waitcnt lgkmcnt(2)");   // I5 ready
    SB0();
    __builtin_amdgcn_s_setprio(1); MFMA8(4, afB, bf1); __builtin_amdgcn_s_setprio(0);
    SB0();

    DSR(afB[0], LA, 6 * 16 + lane15, 1);    // I7: af(m67,kh1)
    DSR(afB[1], LA, 7 * 16 + lane15, 1);
    SB0();
    asm volatile("s_waitcnt lgkmcnt(2)");   // I6 ready
    SB0();
    __builtin_amdgcn_s_setprio(1); MFMA8(6, afA, bf0); __builtin_amdgcn_s_setprio(0);
    SB0();

    asm volatile("s_waitcnt lgkmcnt(0)");   // I7 ready (all reads done)
    SB0();
    __builtin_amdgcn_s_setprio(1); MFMA8(6, afB, bf1); __builtin_amdgcn_s_setprio(0);

    // single cross-wave handshake: my reads done + my stage landed
    asm volatile("s_waitcnt vmcnt(0)" ::: "memory");
    SB0();
    bar_raw();
  }
#undef DSR
#undef MFMA8

  // epilogue: D col = lane&15, row = (lane>>4)*4 + r; mask pad cells to zero
  const int lr = (lane >> 4) * 4, lc = lane & 15;
#pragma unroll
  for (int n = 0; n < 4; ++n) {
    const int col = n0 + wc * 64 + n * 16 + lc;
    if (col < NROW) {
      const int pa = col / 136, pb = col - pa * 136;
      const bool ok = ((unsigned)(pa - 1) < (unsigned)AR[ph]) &&
                      ((unsigned)(pb - 1) < (unsigned)AC[ph]);
#pragma unroll
      for (int m = 0; m < 8; ++m)
#pragma unroll
        for (int r = 0; r < 4; ++r) {
          const int row = oc0 + wr * 128 + m * 16 + lr + r;
          C[((size_t)(ph * OCN + row)) * NROW + col] =
              __float2bfloat16(ok ? acc[m][n][r] : 0.f);
        }
    }
  }
}

// ---- vectorized depthwise 4x4 blur: 8 outputs/thread, branch-free ----
struct __align__(8) U4 { unsigned int w[4]; };

__global__ __launch_bounds__(256) void blur2_k(const unsigned short* __restrict__ C,
                                               float* __restrict__ out) {
  const int tid = threadIdx.x;
  const int t  = tid & 31;                  // col block: n in [8t, 8t+8)
  const int m  = blockIdx.x * 8 + (tid >> 5);
  const int oc = blockIdx.y;
  const float cfv[4] = {0.25f, 0.75f, 0.75f, 0.25f};

  float acc[8];
#pragma unroll
  for (int s = 0; s < 8; ++s) acc[s] = 0.f;

#pragma unroll
  for (int i = 0; i < 4; ++i) {
    const int u  = m - 1 + i;
    const int py = u & 1;
    const int r  = (u >> 1) + 1;
    const size_t base = (size_t)r * 136 + 4 * t;
    const U4 ev = *(const U4*)(C + ((size_t)(py * 2 + 0) * OCN + oc) * NROW + base);
    const U4 ov = *(const U4*)(C + ((size_t)(py * 2 + 1) * OCN + oc) * NROW + base);
    float E[8], O[8];
#pragma unroll
    for (int j = 0; j < 4; ++j) {
      E[2 * j]     = __uint_as_float(ev.w[j] << 16);
      E[2 * j + 1] = __uint_as_float(ev.w[j] & 0xffff0000u);
      O[2 * j]     = __uint_as_float(ov.w[j] << 16);
      O[2 * j + 1] = __uint_as_float(ov.w[j] & 0xffff0000u);
    }
    const float cv = cfv[i];
#pragma unroll
    for (int s = 0; s < 8; ++s) {
      float h;
      if ((s & 1) == 0) {
        const int k = s >> 1;
        h = 0.75f * E[k + 1] + 0.25f * E[k + 2] + 0.25f * O[k] + 0.75f * O[k + 1];
      } else {
        const int k = (s + 1) >> 1;
        h = 0.25f * E[k] + 0.75f * E[k + 1] + 0.75f * O[k] + 0.25f * O[k + 1];
      }
      acc[s] += cv * h;
    }
  }

  float* op = out + ((size_t)oc * 256 + m) * 256 + 8 * t;
  f32x4 s0 = {acc[0], acc[1], acc[2], acc[3]};
  f32x4 s1 = {acc[4], acc[5], acc[6], acc[7]};
  *(f32x4*)op = s0;
  *(f32x4*)(op + 4) = s1;
}

extern "C" void kernel_launch(void* const* d_in, const int* in_sizes, int n_in,
                              void* d_out, int out_size, void* d_ws, size_t ws_size,
                              hipStream_t stream) {
  const float* x = (const float*)d_in[0];
  const float* w = (const float*)d_in[1];
  float* out = (float*)d_out;

  // ws layout (bytes):
  //   AP : 9*512*512*2   = 4,718,592    @ 0
  //   XPT: 17936*512*2   = 18,366,464   @ 4,718,592
  //   C  : 4*512*17792*2 = 72,876,032   @ 23,085,056   (total ~96.0 MB)
  __hip_bfloat16* AP  = (__hip_bfloat16*)d_ws;
  __hip_bfloat16* XPT = (__hip_bfloat16*)((char*)d_ws + 4718592);
  __hip_bfloat16* C   = (__hip_bfloat16*)((char*)d_ws + 23085056);

  wprep_k<<<512, 256, 0, stream>>>(w, AP);
  zguard_k<<<256, 256, 0, stream>>>((unsigned int*)XPT);
  packx2_k<<<dim3(130, 8), 256, 0, stream>>>(x, (unsigned int*)XPT);
  gemm_k<<<dim3(70, 2, 4), 512, 0, stream>>>(AP, XPT, C);
  blur2_k<<<dim3(32, 512), 256, 0, stream>>>((const unsigned short*)C, out);
}